// Round 6
// baseline (473.909 us; speedup 1.0000x reference)
//
#include <hip/hip_runtime.h>
#include <hip/hip_bf16.h>

#define QW 64
#define KW 128
#define PADW 32
#define DEPTH 3
#define HEADS 4
#define B_ 2
#define N_ 8192
#define DS 128
#define DP 16
#define DT 384
#define NT 1024
#define NWIN (N_ / QW)   // 128
#define DH (DS / HEADS)  // 32

typedef unsigned short u16;
typedef __attribute__((ext_vector_type(8))) short short8;
typedef __attribute__((ext_vector_type(4))) float f32x4v;
typedef __attribute__((ext_vector_type(4))) unsigned short us4;
typedef __attribute__((ext_vector_type(2))) short s16x2;

__device__ __forceinline__ u16 f2b(float x) {
    union { float f; unsigned u; } v; v.f = x;
    unsigned r = v.u + 0x7fffu + ((v.u >> 16) & 1u);
    return (u16)(r >> 16);
}
__device__ __forceinline__ float b2f(u16 h) {
    union { unsigned u; float f; } v; v.u = ((unsigned)h) << 16; return v.f;
}
__device__ __forceinline__ unsigned f2b2(float a, float b) {
    __hip_bfloat162 h = __float22bfloat162_rn(make_float2(a, b));
    union { __hip_bfloat162 h; unsigned u; } c; c.h = h; return c.u;
}
__device__ __forceinline__ us4 pack4(float a, float b, float c, float d) {
    union { us4 v; unsigned u[2]; } o;
    o.u[0] = f2b2(a, b);
    o.u[1] = f2b2(c, d);
    return o.v;
}
// relu AFTER packing: bf16 is sign-ordered vs 0 as int16, so packed
// v_pk_max_i16 against 0 == relu on both halves.
__device__ __forceinline__ us4 pack4_relu(float a, float b, float c, float d) {
    union { us4 v; s16x2 s[2]; unsigned u[2]; } o;
    o.u[0] = f2b2(a, b);
    o.u[1] = f2b2(c, d);
    o.s[0] = __builtin_elementwise_max(o.s[0], (s16x2)0);
    o.s[1] = __builtin_elementwise_max(o.s[1], (s16x2)0);
    return o.v;
}

// ---------------------------------------------------------------------------
// DPP cross-lane reductions (VALU, no LDS pipe).
//   0xB1 = quad_perm(1,0,3,2) == xor1     0x4E = quad_perm(2,3,0,1) == xor2
//   0x124 = row_ror:4    0x128 = row_ror:8  (rotation all-reduce over 16)
// ---------------------------------------------------------------------------
template <int CTRL>
__device__ __forceinline__ float fdpp(float x) {
    int r = __builtin_amdgcn_update_dpp(0, __builtin_bit_cast(int, x),
                                        CTRL, 0xF, 0xF, true);
    return __builtin_bit_cast(float, r);
}
__device__ __forceinline__ float sum4_dpp(float x) {
    x += fdpp<0xB1>(x);
    x += fdpp<0x4E>(x);
    return x;
}
__device__ __forceinline__ float sum16_dpp(float x) {
    x += fdpp<0xB1>(x);
    x += fdpp<0x4E>(x);
    x += fdpp<0x124>(x);
    x += fdpp<0x128>(x);
    return x;
}
__device__ __forceinline__ float max16_dpp(float x) {
    x = fmaxf(x, fdpp<0xB1>(x));
    x = fmaxf(x, fdpp<0x4E>(x));
    x = fmaxf(x, fdpp<0x124>(x));
    x = fmaxf(x, fdpp<0x128>(x));
    return x;
}

// ---------------------------------------------------------------------------
// Weight prep (unchanged).
// ---------------------------------------------------------------------------
__global__ __launch_bounds__(256) void convw_kernel(
    const float* __restrict__ Wq, const float* __restrict__ Wk,
    const float* __restrict__ Wv, const float* __restrict__ Wo,
    const float* __restrict__ Wff1, const float* __restrict__ Wff2,
    const float* __restrict__ Wout, const float* __restrict__ Wpff1,
    const float* __restrict__ Wpff2, const float* __restrict__ Wb,
    const float* __restrict__ Wsingle, const float* __restrict__ Wouter,
    u16* __restrict__ qkvT, u16* __restrict__ woT, u16* __restrict__ ff1T,
    u16* __restrict__ ff2T, u16* __restrict__ woutT,
    u16* __restrict__ w1T32, u16* __restrict__ wcatT,
    u16* __restrict__ wsT, u16* __restrict__ woutrT)
{
    int idx = blockIdx.x * 256 + threadIdx.x;
    if (idx < 3 * 384 * 128) {
        int l = idx / (384 * 128), r = idx % (384 * 128);
        int n = r / 128, k = r % 128;
        const float* W = (n < 128) ? Wq : (n < 256) ? Wk : Wv;
        qkvT[idx] = f2b(W[(size_t)l * 16384 + k * 128 + (n & 127)]);
    }
    if (idx < 3 * 128 * 128) {
        int l = idx / 16384, r = idx % 16384;
        int n = r / 128, k = r % 128;
        woT[idx] = f2b(Wo[(size_t)l * 16384 + k * 128 + n]);
    }
    if (idx < 3 * 512 * 128) {
        int l = idx / 65536, r = idx % 65536;
        int n = r / 128, k = r % 128;
        ff1T[idx] = f2b(Wff1[(size_t)l * 65536 + k * 512 + n]);
    }
    if (idx < 3 * 128 * 512) {
        int l = idx / 65536, r = idx % 65536;
        int n = r / 512, k = r % 512;
        ff2T[idx] = f2b(Wff2[(size_t)l * 65536 + k * 128 + n]);
    }
    if (idx < 384 * 128) {
        int n = idx / 128, k = idx % 128;
        woutT[idx] = f2b(Wout[(size_t)k * 384 + n]);
    }
    if (idx < 64 * 32) {
        int n = idx >> 5, k = idx & 31;
        w1T32[idx] = (k < 16) ? f2b(Wpff1[k * 64 + n]) : (u16)0;
    }
    if (idx < 16 * 96) {
        int h = idx / 96, k = idx % 96;
        float s = 0.f;
        if (h < 4) {
            if (k < 16) s = Wb[k * 4 + h];
            else if (k < 80) {
                int j = k - 16;
                for (int c = 0; c < 16; ++c) s += Wpff2[j * 16 + c] * Wb[c * 4 + h];
            }
        }
        wcatT[idx] = f2b(s);
    }
    if (idx < 128 * 416) {
        int n = idx / 416, k = idx % 416;
        float v = 0.f;
        if (k < 128)       v = Wsingle[(5 + k) * 128 + n];
        else if (k < 384)  v = Wsingle[(133 + k - 128) * 128 + n];
        else if (k < 387)  v = Wsingle[(k - 384) * 128 + n];
        else if (k == 387) v = Wsingle[3 * 128 + n];
        else if (k == 388) v = Wsingle[4 * 128 + n];
        wsT[idx] = f2b(v);
    }
    if (idx < 32 * 128) {
        int n = idx >> 7, k = idx & 127;
        woutrT[idx] = f2b(Wouter[k * 32 + n]);
    }
}

// ---------------------------------------------------------------------------
// Embed GEMM + fused LN + P-GEMM + layer-0 QKV GEMM (unchanged).
// ---------------------------------------------------------------------------
__global__ __launch_bounds__(256) void embed_gemm(
    const float* __restrict__ pos, const float* __restrict__ charge,
    const float* __restrict__ mask, const float* __restrict__ elem,
    const float* __restrict__ chars, const u16* __restrict__ wsT,
    const u16* __restrict__ woutrT, const u16* __restrict__ qkv0T,
    float* __restrict__ X, float* __restrict__ P, u16* __restrict__ QKVb)
{
    __shared__ __align__(16) u16 As[64 * 424];
    __shared__ float redS[64][4];
    const int LNOFF = 64 * 136;
    int tid = threadIdx.x;
    int row0 = blockIdx.x * 64;

    #pragma unroll
    for (int it = 0; it < 8; ++it) {
        int idx = tid + it * 256;
        int r = idx >> 5, c4 = idx & 31;
        f32x4v v = *(const f32x4v*)(elem + (size_t)(row0 + r) * 128 + c4 * 4);
        *(us4*)&As[r * 424 + c4 * 4] = pack4(v[0], v[1], v[2], v[3]);
    }
    #pragma unroll
    for (int it = 0; it < 16; ++it) {
        int idx = tid + it * 256;
        int r = idx >> 6, c4 = idx & 63;
        f32x4v v = *(const f32x4v*)(chars + (size_t)(row0 + r) * 256 + c4 * 4);
        *(us4*)&As[r * 424 + 128 + c4 * 4] = pack4(v[0], v[1], v[2], v[3]);
    }
    if (tid < 64) {
        int g = row0 + tid;
        As[tid * 424 + 384] = f2b(pos[g * 3]);
        As[tid * 424 + 385] = f2b(pos[g * 3 + 1]);
        As[tid * 424 + 386] = f2b(pos[g * 3 + 2]);
        As[tid * 424 + 387] = f2b(charge[g]);
        As[tid * 424 + 388] = f2b(mask[g]);
        for (int c = 389; c < 416; ++c) As[tid * 424 + c] = 0;
    }
    __syncthreads();

    int wv = tid >> 6, lane = tid & 63, quad = lane >> 4, l16 = lane & 15;
    int wm = (wv & 1) * 32, wn = (wv >> 1) * 64;
    f32x4v acc[2][4];
    #pragma unroll
    for (int i = 0; i < 2; ++i)
        #pragma unroll
        for (int j = 0; j < 4; ++j) acc[i][j] = (f32x4v){0.f, 0.f, 0.f, 0.f};

    #pragma unroll
    for (int kk = 0; kk < 13; ++kk) {
        short8 a0 = *(short8*)&As[(wm + l16) * 424 + kk * 32 + quad * 8];
        short8 a1 = *(short8*)&As[(wm + 16 + l16) * 424 + kk * 32 + quad * 8];
        #pragma unroll
        for (int nt = 0; nt < 4; ++nt) {
            short8 bw = *(const short8*)&wsT[(size_t)(wn + nt * 16 + l16) * 416 +
                                             kk * 32 + quad * 8];
            acc[0][nt] = __builtin_amdgcn_mfma_f32_16x16x32_bf16(a0, bw, acc[0][nt], 0, 0, 0);
            acc[1][nt] = __builtin_amdgcn_mfma_f32_16x16x32_bf16(a1, bw, acc[1][nt], 0, 0, 0);
        }
    }
    __syncthreads();

    #pragma unroll
    for (int mt = 0; mt < 2; ++mt) {
        #pragma unroll
        for (int r = 0; r < 4; ++r) {
            int lrow = wm + mt * 16 + quad * 4 + r;
            int row = row0 + lrow;
            float s = 0.f, ss = 0.f;
            #pragma unroll
            for (int nt = 0; nt < 4; ++nt) {
                float v = acc[mt][nt][r];
                int col = wn + nt * 16 + l16;
                X[(size_t)row * DS + col] = v;
                As[lrow * 136 + col] = f2b(fmaxf(v, 0.f));
                s += v; ss += v * v;
            }
            s  = sum16_dpp(s);
            ss = sum16_dpp(ss);
            if (l16 == 0) {
                redS[lrow][(wv >> 1) * 2]     = s;
                redS[lrow][(wv >> 1) * 2 + 1] = ss;
            }
        }
    }
    __syncthreads();

    #pragma unroll
    for (int mt = 0; mt < 2; ++mt)
        #pragma unroll
        for (int r = 0; r < 4; ++r) {
            int lrow = wm + mt * 16 + quad * 4 + r;
            f32x4v rv = *(f32x4v*)&redS[lrow][0];
            float s = rv[0] + rv[2], ss = rv[1] + rv[3];
            float m = s * (1.f / 128.f);
            float var = ss * (1.f / 128.f) - m * m;
            float rs = __builtin_amdgcn_rsqf(var + 1e-5f);
            #pragma unroll
            for (int nt = 0; nt < 4; ++nt) {
                int col = wn + nt * 16 + l16;
                As[LNOFF + lrow * 136 + col] = f2b((acc[mt][nt][r] - m) * rs);
            }
        }

    {
        f32x4v pacc[2];
        pacc[0] = (f32x4v){0.f, 0.f, 0.f, 0.f};
        pacc[1] = (f32x4v){0.f, 0.f, 0.f, 0.f};
        #pragma unroll
        for (int ks = 0; ks < 4; ++ks) {
            short8 a = *(short8*)&As[(wv * 16 + l16) * 136 + ks * 32 + quad * 8];
            #pragma unroll
            for (int nt = 0; nt < 2; ++nt) {
                short8 bw = *(const short8*)&woutrT[(size_t)(nt * 16 + l16) * 128 +
                                                    ks * 32 + quad * 8];
                pacc[nt] = __builtin_amdgcn_mfma_f32_16x16x32_bf16(a, bw, pacc[nt], 0, 0, 0);
            }
        }
        #pragma unroll
        for (int nt = 0; nt < 2; ++nt)
            #pragma unroll
            for (int r = 0; r < 4; ++r) {
                int row = row0 + wv * 16 + quad * 4 + r;
                P[(size_t)row * 32 + nt * 16 + l16] = pacc[nt][r];
            }
    }
    __syncthreads();

    for (int c = 0; c < 3; ++c) {
        int n0c = c * 128;
        f32x4v qa[2][4];
        #pragma unroll
        for (int i = 0; i < 2; ++i)
            #pragma unroll
            for (int j = 0; j < 4; ++j) qa[i][j] = (f32x4v){0.f, 0.f, 0.f, 0.f};
        #pragma unroll
        for (int ks = 0; ks < 4; ++ks) {
            short8 a0 = *(short8*)&As[LNOFF + (wm + l16) * 136 + ks * 32 + quad * 8];
            short8 a1 = *(short8*)&As[LNOFF + (wm + 16 + l16) * 136 + ks * 32 + quad * 8];
            #pragma unroll
            for (int nt = 0; nt < 4; ++nt) {
                short8 bw = *(const short8*)&qkv0T[(size_t)(n0c + wn + nt * 16 + l16) * 128 +
                                                   ks * 32 + quad * 8];
                qa[0][nt] = __builtin_amdgcn_mfma_f32_16x16x32_bf16(a0, bw, qa[0][nt], 0, 0, 0);
                qa[1][nt] = __builtin_amdgcn_mfma_f32_16x16x32_bf16(a1, bw, qa[1][nt], 0, 0, 0);
            }
        }
        #pragma unroll
        for (int mt = 0; mt < 2; ++mt)
            #pragma unroll
            for (int nt = 0; nt < 4; ++nt)
                #pragma unroll
                for (int r = 0; r < 4; ++r) {
                    int row = row0 + wm + mt * 16 + quad * 4 + r;
                    int col = n0c + wn + nt * 16 + l16;
                    QKVb[(size_t)row * 384 + col] = f2b(qa[mt][nt][r]);
                }
    }
}

// ---------------------------------------------------------------------------
// Bias kernel (unchanged).
// ---------------------------------------------------------------------------
__global__ __launch_bounds__(256) void bias_kernel(
    const float* __restrict__ pos, const int* __restrict__ uid,
    const float* __restrict__ P, const float* __restrict__ Wpair,
    const u16* __restrict__ w1T32, const u16* __restrict__ wcatT,
    u16* __restrict__ BIASb)
{
    __shared__ __align__(16) float posjS[128][4];
    __shared__ __align__(16) u16 lpS[4][16 * 24];
    __shared__ __align__(16) u16 A2S[4][16 * 104];

    int tid = threadIdx.x;
    int b  = blockIdx.x >> 11;
    int w  = (blockIdx.x >> 4) & 127;
    int qg = blockIdx.x & 15;

    if (tid < 128) {
        int r = tid;
        int jk = w * QW + r - PADW;
        bool valid = (jk >= 0) && (jk < N_);
        int gk = b * N_ + jk;
        float x = 0.f, y = 0.f, zz = 0.f; int u = 0;
        if (valid) { x = pos[gk * 3]; y = pos[gk * 3 + 1]; zz = pos[gk * 3 + 2]; u = uid[gk]; }
        posjS[r][0] = x; posjS[r][1] = y; posjS[r][2] = zz;
        ((int*)posjS[r])[3] = u;
    }

    int wv = tid >> 6, lane = tid & 63, quad = lane >> 4, l16 = lane & 15;
    int cl = lane >> 2, cg = lane & 3;
    int q = qg * 4 + wv;
    int gq = b * N_ + w * QW + q;

    float xi = pos[gq * 3], yi = pos[gq * 3 + 1], zi = pos[gq * 3 + 2];
    int ui = uid[gq];
    f32x4v pi4 = *(const f32x4v*)(P + (size_t)gq * 32 + cg * 4);
    f32x4v wp[5];
    #pragma unroll
    for (int f = 0; f < 5; ++f)
        wp[f] = *(const f32x4v*)(Wpair + f * 16 + cg * 4);
    short8 w1f[4], wcat[3];
    #pragma unroll
    for (int nt = 0; nt < 4; ++nt)
        w1f[nt] = *(const short8*)&w1T32[(nt * 16 + l16) * 32 + quad * 8];
    #pragma unroll
    for (int ks = 0; ks < 3; ++ks)
        wcat[ks] = *(const short8*)&wcatT[l16 * 96 + ks * 32 + quad * 8];

    f32x4v pjv[8];
    #pragma unroll
    for (int t = 0; t < 8; ++t) {
        int jk = w * QW + t * 16 + cl - PADW;
        bool valid = (jk >= 0) && (jk < N_);
        int gk = b * N_ + jk;
        f32x4v v = (f32x4v){0.f, 0.f, 0.f, 0.f};
        if (valid) v = *(const f32x4v*)(P + (size_t)gk * 32 + 16 + cg * 4);
        pjv[t] = v;
    }

    *(us4*)&A2S[wv][l16 * 104 + 80 + quad * 4] = (us4){0, 0, 0, 0};
    __syncthreads();

    size_t bbase = ((size_t)(b * NWIN + w) * HEADS) * (QW * KW);
    const short8 zero8 = (short8){0, 0, 0, 0, 0, 0, 0, 0};

    #pragma unroll 2
    for (int t = 0; t < 8; ++t) {
        int kk1 = t * 16 + cl;
        f32x4v pj4 = *(const f32x4v*)&posjS[kk1][0];
        float xj = pj4[0], yj = pj4[1], zj = pj4[2];
        int uj = __float_as_int(pj4[3]);
        float dx = xi - xj, dy = yi - yj, dz = zi - zj;
        float inv = __builtin_amdgcn_rcpf(1.f + dx * dx + dy * dy + dz * dz);
        float bf = (ui == uj) ? 1.f : 0.f;
        float pr[4];
        #pragma unroll
        for (int j = 0; j < 4; ++j) {
            float s = fmaf(dx, wp[0][j], fmaf(dy, wp[1][j],
                      fmaf(dz, wp[2][j], fmaf(inv, wp[3][j], wp[4][j]))));
            pr[j] = fmaf(bf, s, pi4[j] + pjv[t][j]);
        }
        float sum = pr[0] + pr[1] + pr[2] + pr[3];
        sum = sum4_dpp(sum);
        float m = sum * (1.f / 16.f);
        float d0 = pr[0] - m, d1 = pr[1] - m, d2 = pr[2] - m, d3 = pr[3] - m;
        float vs = d0 * d0 + d1 * d1 + d2 * d2 + d3 * d3;
        vs = sum4_dpp(vs);
        float rstd = __builtin_amdgcn_rsqf(vs * (1.f / 16.f) + 1e-5f);
        *(us4*)&lpS[wv][cl * 24 + cg * 4] =
            pack4(d0 * rstd, d1 * rstd, d2 * rstd, d3 * rstd);
        *(us4*)&A2S[wv][cl * 104 + cg * 4] = pack4(pr[0], pr[1], pr[2], pr[3]);

        short8 blp = zero8;
        if (quad < 2) blp = *(short8*)&lpS[wv][l16 * 24 + quad * 8];
        #pragma unroll
        for (int nt = 0; nt < 4; ++nt) {
            f32x4v z4 = (f32x4v){0.f, 0.f, 0.f, 0.f};
            z4 = __builtin_amdgcn_mfma_f32_16x16x32_bf16(w1f[nt], blp, z4, 0, 0, 0);
            *(us4*)&A2S[wv][l16 * 104 + 16 + nt * 16 + quad * 4] =
                pack4_relu(z4[0], z4[1], z4[2], z4[3]);
        }
        f32x4v acc = (f32x4v){0.f, 0.f, 0.f, 0.f};
        #pragma unroll
        for (int ks = 0; ks < 3; ++ks) {
            short8 a2 = *(short8*)&A2S[wv][l16 * 104 + ks * 32 + quad * 8];
            acc = __builtin_amdgcn_mfma_f32_16x16x32_bf16(a2, wcat[ks], acc, 0, 0, 0);
        }
        if (l16 < 4) {
            *(us4*)&BIASb[bbase + (size_t)l16 * (QW * KW) + q * KW +
                          t * 16 + quad * 4] = pack4(acc[0], acc[1], acc[2], acc[3]);
        }
    }
}

// ---------------------------------------------------------------------------
// wo_ff_fused<LAST> r18: WAVE-AUTONOMOUS, ZERO barriers.
// r2-r5 post-mortem: occupancy x inflight-per-wave stayed constant across
// 4 interventions -> the 7-barrier lockstep structure itself was the cap.
// New structure: each wave owns 16 rows and runs the full chain
// (Wo -> resid+LN -> FF1 -> FF2 -> resid+LN -> aux) independently:
//  * LN fully in-wave: row sum = in-register sum over 8 nt + sum16_dpp.
//  * LDS = per-wave transpose scratch only; same-wave write->read is
//    lgkmcnt-ordered (the attn_kernel pattern), no barrier.
//  * No barriers => compiler freely hoists weight loads over MFMAs (ILP).
//  * grid 256 x 4 waves = 1 wave/SIMD: VGPR is free, use it.
//  * LAST skips the dead X write-back.
// ---------------------------------------------------------------------------
template <bool LAST>
__global__ __launch_bounds__(256) void wo_ff_fused(
    const u16* __restrict__ Ob, const u16* __restrict__ woT,
    const u16* __restrict__ w1T, const u16* __restrict__ w2T,
    const u16* __restrict__ auxT, float* __restrict__ X,
    u16* __restrict__ OutB)
{
    __shared__ __align__(16) u16 AsW[4][16 * 136];  // 4 x 4.25 KB
    __shared__ __align__(16) u16 HsW[4][16 * 520];  // 4 x 16.25 KB
    int tid = threadIdx.x;
    int wv = tid >> 6, lane = tid & 63, quad = lane >> 4, l16 = lane & 15;
    int row0 = blockIdx.x * 64 + wv * 16;
    u16* As = AsW[wv];
    u16* Hs = HsW[wv];

    // ---- Wo GEMM: A-frags direct from global, + residual ----
    short8 af[4];
    #pragma unroll
    for (int ks = 0; ks < 4; ++ks)
        af[ks] = *(const short8*)&Ob[(size_t)(row0 + l16) * 128 + ks * 32 + quad * 8];

    f32x4v acc[8];
    #pragma unroll
    for (int nt = 0; nt < 8; ++nt) {
        f32x4v a = (f32x4v){0.f, 0.f, 0.f, 0.f};
        #pragma unroll
        for (int ks = 0; ks < 4; ++ks) {
            short8 b = *(const short8*)&woT[(size_t)(nt * 16 + l16) * 128 +
                                            ks * 32 + quad * 8];
            a = __builtin_amdgcn_mfma_f32_16x16x32_bf16(af[ks], b, a, 0, 0, 0);
        }
        #pragma unroll
        for (int r = 0; r < 4; ++r)
            a[r] += X[(size_t)(row0 + quad * 4 + r) * DS + nt * 16 + l16];
        acc[nt] = a;
    }

    // ---- LN1 fully in-wave -> As scratch (bf16, [row][col]) ----
    #pragma unroll
    for (int r = 0; r < 4; ++r) {
        float s = 0.f, ss = 0.f;
        #pragma unroll
        for (int nt = 0; nt < 8; ++nt) {
            float v = acc[nt][r];
            s += v; ss += v * v;
        }
        s  = sum16_dpp(s);
        ss = sum16_dpp(ss);
        float m = s * (1.f / 128.f);
        float var = ss * (1.f / 128.f) - m * m;
        float rs = __builtin_amdgcn_rsqf(var + 1e-5f);
        #pragma unroll
        for (int nt = 0; nt < 8; ++nt)
            As[(quad * 4 + r) * 136 + nt * 16 + l16] = f2b((acc[nt][r] - m) * rs);
    }

    // ---- FF1: H = relu(LN(x) @ W1), full 512 cols, out transposed to Hs ----
    {
        short8 brow[4];
        #pragma unroll
        for (int ks = 0; ks < 4; ++ks)
            brow[ks] = *(short8*)&As[l16 * 136 + ks * 32 + quad * 8];
        #pragma unroll
        for (int mt = 0; mt < 32; ++mt) {
            f32x4v c0 = (f32x4v){0.f, 0.f, 0.f, 0.f};
            #pragma unroll
            for (int ks = 0; ks < 4; ++ks) {
                short8 aw = *(const short8*)&w1T[(size_t)(mt * 16 + l16) * 128 +
                                                 ks * 32 + quad * 8];
                c0 = __builtin_amdgcn_mfma_f32_16x16x32_bf16(aw, brow[ks], c0, 0, 0, 0);
            }
            *(us4*)&Hs[l16 * 520 + mt * 16 + quad * 4] =
                pack4_relu(c0[0], c0[1], c0[2], c0[3]);
        }
    }

    // ---- FF2: 16 x 128 x 512 ----
    f32x4v acc2[8];
    #pragma unroll
    for (int nt = 0; nt < 8; ++nt) acc2[nt] = (f32x4v){0.f, 0.f, 0.f, 0.f};
    #pragma unroll
    for (int kb = 0; kb < 4; ++kb) {
        short8 hf[4];
        #pragma unroll
        for (int ksl = 0; ksl < 4; ++ksl)
            hf[ksl] = *(short8*)&Hs[l16 * 520 + (kb * 4 + ksl) * 32 + quad * 8];
        #pragma unroll
        for (int nt = 0; nt < 8; ++nt)
            #pragma unroll
            for (int ksl = 0; ksl < 4; ++ksl) {
                short8 b = *(const short8*)&w2T[(size_t)(nt * 16 + l16) * 512 +
                                                (kb * 4 + ksl) * 32 + quad * 8];
                acc2[nt] = __builtin_amdgcn_mfma_f32_16x16x32_bf16(hf[ksl], b, acc2[nt], 0, 0, 0);
            }
    }

    // ---- residual2 (+X write unless LAST) + LN2 in-wave -> As ----
    #pragma unroll
    for (int r = 0; r < 4; ++r) {
        float vv[8];
        float s = 0.f, ss = 0.f;
        #pragma unroll
        for (int nt = 0; nt < 8; ++nt) {
            float v = acc2[nt][r] + acc[nt][r];
            vv[nt] = v;
            if (!LAST)
                X[(size_t)(row0 + quad * 4 + r) * DS + nt * 16 + l16] = v;
            s += v; ss += v * v;
        }
        float m = 0.f, rs = 1.f;
        if (!LAST) {
            s  = sum16_dpp(s);
            ss = sum16_dpp(ss);
            m = s * (1.f / 128.f);
            float var = ss * (1.f / 128.f) - m * m;
            rs = __builtin_amdgcn_rsqf(var + 1e-5f);
        }
        #pragma unroll
        for (int nt = 0; nt < 8; ++nt)
            As[(quad * 4 + r) * 136 + nt * 16 + l16] =
                f2b(LAST ? vv[nt] : (vv[nt] - m) * rs);
    }

    // ---- output GEMM: 16 x 384 x 128 (next-layer QKV, or W_out+relu) ----
    {
        short8 arow[4];
        #pragma unroll
        for (int ks = 0; ks < 4; ++ks)
            arow[ks] = *(short8*)&As[l16 * 136 + ks * 32 + quad * 8];
        #pragma unroll
        for (int t = 0; t < 24; ++t) {
            f32x4v qa = (f32x4v){0.f, 0.f, 0.f, 0.f};
            #pragma unroll
            for (int ks = 0; ks < 4; ++ks) {
                short8 b = *(const short8*)&auxT[(size_t)(t * 16 + l16) * 128 +
                                                 ks * 32 + quad * 8];
                qa = __builtin_amdgcn_mfma_f32_16x16x32_bf16(arow[ks], b, qa, 0, 0, 0);
            }
            #pragma unroll
            for (int r = 0; r < 4; ++r) {
                float v = qa[r];
                if (LAST) v = fmaxf(v, 0.f);
                OutB[(size_t)(row0 + quad * 4 + r) * 384 + t * 16 + l16] = f2b(v);
            }
        }
    }
}

// ---------------------------------------------------------------------------
// Windowed attention v9 (unchanged).
// ---------------------------------------------------------------------------
__global__ __launch_bounds__(256) void attn_kernel(
    const u16* __restrict__ QKV, const u16* __restrict__ BIASb,
    u16* __restrict__ O)
{
    __shared__ __align__(16) u16 sQ[64 * 40];    // 5 KB
    __shared__ __align__(16) u16 sK[128 * 40];   // 10 KB
    __shared__ __align__(16) u16 sVt[32 * 152];  // 9.5 KB
    __shared__ __align__(16) u16 sP[64 * 136];   // bias tile, then P (17 KB)

    int tid = threadIdx.x;
    int h = blockIdx.x & 3, w = (blockIdx.x >> 2) & 127, b = blockIdx.x >> 9;
    size_t rowbase = (size_t)b * N_ + w * QW;
    size_t bbase = ((size_t)(b * NWIN + w) * HEADS + h) * (QW * KW);
    const short8 zero8 = (short8){0, 0, 0, 0, 0, 0, 0, 0};
    const bool edge = (w == 0) || (w == NWIN - 1);

    {   // Q
        int r = tid >> 2, d8 = (tid & 3) * 8;
        *(short8*)&sQ[r * 40 + d8] =
            *(const short8*)&QKV[(rowbase + r) * 384 + h * DH + d8];
    }
    #pragma unroll
    for (int i = 0; i < 2; ++i) {  // K
        int idx = tid + i * 256;
        int r = idx >> 2, d8 = (idx & 3) * 8;
        int jk = w * QW + r - PADW;
        short8 v = zero8;
        if (jk >= 0 && jk < N_)
            v = *(const short8*)&QKV[((size_t)b * N_ + jk) * 384 + 128 + h * DH + d8];
        *(short8*)&sK[r * 40 + d8] = v;
    }
    {   // V transposed
        int kk = tid >> 1, d0 = (tid & 1) * 16;
        int jk = w * QW + kk - PADW;
        short8 v0 = zero8, v1 = zero8;
        if (jk >= 0 && jk < N_) {
            const u16* src = &QKV[((size_t)b * N_ + jk) * 384 + 256 + h * DH + d0];
            v0 = *(const short8*)src;
            v1 = *(const short8*)(src + 8);
        }
        #pragma unroll
        for (int j = 0; j < 8; ++j) {
            sVt[(d0 + j) * 152 + kk] = (u16)v0[j];
            sVt[(d0 + 8 + j) * 152 + kk] = (u16)v1[j];
        }
    }
    #pragma unroll
    for (int i = 0; i < 4; ++i) {  // bias tile -> sP
        int idx = tid + i * 256;
        int q = idx >> 4, c8 = idx & 15;
        *(short8*)&sP[q * 136 + c8 * 8] =
            *(const short8*)&BIASb[bbase + (size_t)q * KW + c8 * 8];
    }
    __syncthreads();  // the ONLY barrier

    int wv = tid >> 6, lane = tid & 63, quad = lane >> 4, l16 = lane & 15;
    const float scale = 0.17677669529663687f;  // 1/sqrt(32)

    // ---- QK^T: wave's 16 q rows x full 128 kk ----
    short8 aq = *(short8*)&sQ[(wv * 16 + l16) * 40 + quad * 8];
    float e[8][4];
    #pragma unroll
    for (int nt = 0; nt < 8; ++nt) {
        short8 bk = *(short8*)&sK[(nt * 16 + l16) * 40 + quad * 8];
        f32x4v acc = (f32x4v){0.f, 0.f, 0.f, 0.f};
        acc = __builtin_amdgcn_mfma_f32_16x16x32_bf16(aq, bk, acc, 0, 0, 0);
        int kk = nt * 16 + l16;
        float msk = 0.f;
        if (edge) {
            int jk = w * QW + kk - PADW;
            msk = (jk >= 0 && jk < N_) ? 0.f : -1e9f;
        }
        #pragma unroll
        for (int r = 0; r < 4; ++r) {
            int q = wv * 16 + quad * 4 + r;
            e[nt][r] = acc[r] * scale + b2f(sP[q * 136 + kk]) + msk;
        }
    }

    // ---- softmax fully within the wave (DPP row reductions) ----
    #pragma unroll
    for (int r = 0; r < 4; ++r) {
        float m = e[0][r];
        #pragma unroll
        for (int nt = 1; nt < 8; ++nt) m = fmaxf(m, e[nt][r]);
        m = max16_dpp(m);
        float s = 0.f;
        #pragma unroll
        for (int nt = 0; nt < 8; ++nt) {
            float ev = __expf(e[nt][r] - m);
            e[nt][r] = ev;
            s += ev;
        }
        s = sum16_dpp(s);
        float inv = __builtin_amdgcn_rcpf(s);
        #pragma unroll
        for (int nt = 0; nt < 8; ++nt) e[nt][r] *= inv;
    }

    // ---- write P into the wave's OWN sP rows (in-wave ordering only) ----
    #pragma unroll
    for (int nt = 0; nt < 8; ++nt) {
        int kk = nt * 16 + l16;
        #pragma unroll
        for (int r = 0; r < 4; ++r) {
            int q = wv * 16 + quad * 4 + r;
            sP[q * 136 + kk] = f2b(e[nt][r]);
        }
    }

    // ---- P @ V (reads the wave's own rows; lgkmcnt-ordered, no barrier) ----
    short8 ap[4];
    #pragma unroll
    for (int ks = 0; ks < 4; ++ks)
        ap[ks] = *(short8*)&sP[(wv * 16 + l16) * 136 + ks * 32 + quad * 8];
    #pragma unroll
    for (int nt = 0; nt < 2; ++nt) {
        f32x4v acc = (f32x4v){0.f, 0.f, 0.f, 0.f};
        #pragma unroll
        for (int ks = 0; ks < 4; ++ks) {
            short8 bv = *(short8*)&sVt[(nt * 16 + l16) * 152 + ks * 32 + quad * 8];
            acc = __builtin_amdgcn_mfma_f32_16x16x32_bf16(ap[ks], bv, acc, 0, 0, 0);
        }
        int d = nt * 16 + l16;
        #pragma unroll
        for (int r = 0; r < 4; ++r) {
            int q = wv * 16 + quad * 4 + r;
            O[(rowbase + q) * DS + h * DH + d] = f2b(acc[r]);
        }
    }
}

// ---------------------------------------------------------------------------
// Segment mean (unchanged).
// ---------------------------------------------------------------------------
__global__ __launch_bounds__(128) void seg_kernel(
    const u16* __restrict__ TOKb, const int* __restrict__ idx,
    float* __restrict__ out)
{
    int t = blockIdx.x & (NT - 1);
    int b = blockIdx.x >> 10;
    const int* id = idx + (size_t)b * N_;

    int lo = 0, hi = N_;
    while (lo < hi) { int mid = (lo + hi) >> 1; if (id[mid] < t) lo = mid + 1; else hi = mid; }
    int start = lo;
    hi = N_;
    while (lo < hi) { int mid = (lo + hi) >> 1; if (id[mid] < t + 1) lo = mid + 1; else hi = mid; }
    int end = lo;

    float inv = 1.f / fmaxf((float)(end - start), 1.f);
    if (threadIdx.x < 96) {
        int c4 = threadIdx.x * 4;
        f32x4v s = (f32x4v){0.f, 0.f, 0.f, 0.f};
        for (int r = start; r < end; ++r) {
            us4 v = *(const us4*)&TOKb[((size_t)b * N_ + r) * DT + c4];
            s[0] += b2f(v[0]); s[1] += b2f(v[1]);
            s[2] += b2f(v[2]); s[3] += b2f(v[3]);
        }
        s[0] *= inv; s[1] *= inv; s[2] *= inv; s[3] *= inv;
        *(f32x4v*)&out[((size_t)b * NT + t) * DT + c4] = s;
    }
}

// ---------------------------------------------------------------------------
extern "C" void kernel_launch(void* const* d_in, const int* in_sizes, int n_in,
                              void* d_out, int out_size, void* d_ws, size_t ws_size,
                              hipStream_t stream)
{
    const float* ref_pos    = (const float*)d_in[0];
    const float* ref_charge = (const float*)d_in[1];
    const float* ref_mask   = (const float*)d_in[2];
    const float* ref_elem   = (const float*)d_in[3];
    const float* ref_chars  = (const float*)d_in[4];
    const float* W_single   = (const float*)d_in[5];
    const float* W_pair     = (const float*)d_in[6];
    const float* W_outer    = (const float*)d_in[7];
    const float* Wp_ff1     = (const float*)d_in[8];
    const float* Wp_ff2     = (const float*)d_in[9];
    const float* Wq         = (const float*)d_in[10];
    const float* Wk         = (const float*)d_in[11];
    const float* Wv         = (const float*)d_in[12];
    const float* Wo         = (const float*)d_in[13];
    const float* Wb         = (const float*)d_in[14];
    const float* Wff1       = (const float*)d_in[15];
    const float* Wff2       = (const float*)d_in[16];
    const float* W_out      = (const float*)d_in[17];
    const int*   uid        = (const int*)d_in[18];
    const int*   a2t        = (const int*)d_in[19];
    float* out = (float*)d_out;

    const size_t ROWS = (size_t)B_ * N_;  // 16384
    float* ws = (float*)d_ws;
    float* X    = ws;
    float* P    = X + ROWS * DS;
    u16* QKVb   = (u16*)(P + ROWS * 32);
    u16* Ob     = QKVb + ROWS * 384;
    u16* FFb    = Ob + ROWS * DS;          // unused (layout stability)
    u16* BIASb  = FFb + ROWS * 512;
    u16* TOKb   = BIASb + (size_t)B_ * NWIN * HEADS * QW * KW;
    u16* LNb    = TOKb + ROWS * DT;        // unused
    u16* qkvT   = LNb + ROWS * DS;
    u16* woT    = qkvT + 3 * 384 * 128;
    u16* ff1T   = woT + 3 * 128 * 128;
    u16* ff2T   = ff1T + 3 * 512 * 128;
    u16* woutT  = ff2T + 3 * 128 * 512;
    u16* w1T32  = woutT + 384 * 128;
    u16* wcatT  = w1T32 + 64 * 32;
    u16* wsT    = wcatT + 16 * 96;
    u16* woutrT = wsT + 128 * 416;

    convw_kernel<<<768, 256, 0, stream>>>(Wq, Wk, Wv, Wo, Wff1, Wff2, W_out,
                                          Wp_ff1, Wp_ff2, Wb, W_single, W_outer,
                                          qkvT, woT, ff1T, ff2T, woutT,
                                          w1T32, wcatT, wsT, woutrT);
    embed_gemm<<<ROWS / 64, 256, 0, stream>>>(ref_pos, ref_charge, ref_mask,
                                              ref_elem, ref_chars, wsT, woutrT,
                                              qkvT, X, P, QKVb);
    bias_kernel<<<4096, 256, 0, stream>>>(ref_pos, uid, P, W_pair,
                                          w1T32, wcatT, BIASb);

    for (int l = 0; l < DEPTH; ++l) {
        attn_kernel<<<B_ * NWIN * HEADS, 256, 0, stream>>>(QKVb, BIASb, Ob);
        if (l < DEPTH - 1) {
            wo_ff_fused<false><<<ROWS / 64, 256, 0, stream>>>(
                Ob, woT + (size_t)l * 128 * 128,
                ff1T + (size_t)l * 512 * 128, ff2T + (size_t)l * 128 * 512,
                qkvT + (size_t)(l + 1) * 384 * 128, X, QKVb);
        } else {
            wo_ff_fused<true><<<ROWS / 64, 256, 0, stream>>>(
                Ob, woT + (size_t)l * 128 * 128,
                ff1T + (size_t)l * 512 * 128, ff2T + (size_t)l * 128 * 512,
                woutT, X, TOKb);
        }
    }

    seg_kernel<<<B_ * NT, 128, 0, stream>>>(TOKb, a2t, out);
}

// Round 7
// 373.734 us; speedup vs baseline: 1.2680x; 1.2680x over previous
//
#include <hip/hip_runtime.h>
#include <hip/hip_bf16.h>

#define QW 64
#define KW 128
#define PADW 32
#define DEPTH 3
#define HEADS 4
#define B_ 2
#define N_ 8192
#define DS 128
#define DP 16
#define DT 384
#define NT 1024
#define NWIN (N_ / QW)   // 128
#define DH (DS / HEADS)  // 32

typedef unsigned short u16;
typedef __attribute__((ext_vector_type(8))) short short8;
typedef __attribute__((ext_vector_type(4))) float f32x4v;
typedef __attribute__((ext_vector_type(4))) unsigned short us4;
typedef __attribute__((ext_vector_type(2))) short s16x2;

__device__ __forceinline__ u16 f2b(float x) {
    union { float f; unsigned u; } v; v.f = x;
    unsigned r = v.u + 0x7fffu + ((v.u >> 16) & 1u);
    return (u16)(r >> 16);
}
__device__ __forceinline__ float b2f(u16 h) {
    union { unsigned u; float f; } v; v.u = ((unsigned)h) << 16; return v.f;
}
__device__ __forceinline__ unsigned f2b2(float a, float b) {
    __hip_bfloat162 h = __float22bfloat162_rn(make_float2(a, b));
    union { __hip_bfloat162 h; unsigned u; } c; c.h = h; return c.u;
}
__device__ __forceinline__ us4 pack4(float a, float b, float c, float d) {
    union { us4 v; unsigned u[2]; } o;
    o.u[0] = f2b2(a, b);
    o.u[1] = f2b2(c, d);
    return o.v;
}
// relu AFTER packing: bf16 is sign-ordered vs 0 as int16, so packed
// v_pk_max_i16 against 0 == relu on both halves.
__device__ __forceinline__ us4 pack4_relu(float a, float b, float c, float d) {
    union { us4 v; s16x2 s[2]; unsigned u[2]; } o;
    o.u[0] = f2b2(a, b);
    o.u[1] = f2b2(c, d);
    o.s[0] = __builtin_elementwise_max(o.s[0], (s16x2)0);
    o.s[1] = __builtin_elementwise_max(o.s[1], (s16x2)0);
    return o.v;
}

// ---------------------------------------------------------------------------
// DPP cross-lane reductions (VALU, no LDS pipe).
//   0xB1 = quad_perm(1,0,3,2) == xor1     0x4E = quad_perm(2,3,0,1) == xor2
//   0x124 = row_ror:4    0x128 = row_ror:8  (rotation all-reduce over 16)
// ---------------------------------------------------------------------------
template <int CTRL>
__device__ __forceinline__ float fdpp(float x) {
    int r = __builtin_amdgcn_update_dpp(0, __builtin_bit_cast(int, x),
                                        CTRL, 0xF, 0xF, true);
    return __builtin_bit_cast(float, r);
}
__device__ __forceinline__ float sum4_dpp(float x) {
    x += fdpp<0xB1>(x);
    x += fdpp<0x4E>(x);
    return x;
}
__device__ __forceinline__ float sum16_dpp(float x) {
    x += fdpp<0xB1>(x);
    x += fdpp<0x4E>(x);
    x += fdpp<0x124>(x);
    x += fdpp<0x128>(x);
    return x;
}
__device__ __forceinline__ float max16_dpp(float x) {
    x = fmaxf(x, fdpp<0xB1>(x));
    x = fmaxf(x, fdpp<0x4E>(x));
    x = fmaxf(x, fdpp<0x124>(x));
    x = fmaxf(x, fdpp<0x128>(x));
    return x;
}

// ---------------------------------------------------------------------------
// Weight prep (unchanged).
// ---------------------------------------------------------------------------
__global__ __launch_bounds__(256) void convw_kernel(
    const float* __restrict__ Wq, const float* __restrict__ Wk,
    const float* __restrict__ Wv, const float* __restrict__ Wo,
    const float* __restrict__ Wff1, const float* __restrict__ Wff2,
    const float* __restrict__ Wout, const float* __restrict__ Wpff1,
    const float* __restrict__ Wpff2, const float* __restrict__ Wb,
    const float* __restrict__ Wsingle, const float* __restrict__ Wouter,
    u16* __restrict__ qkvT, u16* __restrict__ woT, u16* __restrict__ ff1T,
    u16* __restrict__ ff2T, u16* __restrict__ woutT,
    u16* __restrict__ w1T32, u16* __restrict__ wcatT,
    u16* __restrict__ wsT, u16* __restrict__ woutrT)
{
    int idx = blockIdx.x * 256 + threadIdx.x;
    if (idx < 3 * 384 * 128) {
        int l = idx / (384 * 128), r = idx % (384 * 128);
        int n = r / 128, k = r % 128;
        const float* W = (n < 128) ? Wq : (n < 256) ? Wk : Wv;
        qkvT[idx] = f2b(W[(size_t)l * 16384 + k * 128 + (n & 127)]);
    }
    if (idx < 3 * 128 * 128) {
        int l = idx / 16384, r = idx % 16384;
        int n = r / 128, k = r % 128;
        woT[idx] = f2b(Wo[(size_t)l * 16384 + k * 128 + n]);
    }
    if (idx < 3 * 512 * 128) {
        int l = idx / 65536, r = idx % 65536;
        int n = r / 128, k = r % 128;
        ff1T[idx] = f2b(Wff1[(size_t)l * 65536 + k * 512 + n]);
    }
    if (idx < 3 * 128 * 512) {
        int l = idx / 65536, r = idx % 65536;
        int n = r / 512, k = r % 512;
        ff2T[idx] = f2b(Wff2[(size_t)l * 65536 + k * 128 + n]);
    }
    if (idx < 384 * 128) {
        int n = idx / 128, k = idx % 128;
        woutT[idx] = f2b(Wout[(size_t)k * 384 + n]);
    }
    if (idx < 64 * 32) {
        int n = idx >> 5, k = idx & 31;
        w1T32[idx] = (k < 16) ? f2b(Wpff1[k * 64 + n]) : (u16)0;
    }
    if (idx < 16 * 96) {
        int h = idx / 96, k = idx % 96;
        float s = 0.f;
        if (h < 4) {
            if (k < 16) s = Wb[k * 4 + h];
            else if (k < 80) {
                int j = k - 16;
                for (int c = 0; c < 16; ++c) s += Wpff2[j * 16 + c] * Wb[c * 4 + h];
            }
        }
        wcatT[idx] = f2b(s);
    }
    if (idx < 128 * 416) {
        int n = idx / 416, k = idx % 416;
        float v = 0.f;
        if (k < 128)       v = Wsingle[(5 + k) * 128 + n];
        else if (k < 384)  v = Wsingle[(133 + k - 128) * 128 + n];
        else if (k < 387)  v = Wsingle[(k - 384) * 128 + n];
        else if (k == 387) v = Wsingle[3 * 128 + n];
        else if (k == 388) v = Wsingle[4 * 128 + n];
        wsT[idx] = f2b(v);
    }
    if (idx < 32 * 128) {
        int n = idx >> 7, k = idx & 127;
        woutrT[idx] = f2b(Wouter[k * 32 + n]);
    }
}

// ---------------------------------------------------------------------------
// Embed GEMM + fused LN + P-GEMM + layer-0 QKV GEMM (r5 known-good).
// ---------------------------------------------------------------------------
__global__ __launch_bounds__(256) void embed_gemm(
    const float* __restrict__ pos, const float* __restrict__ charge,
    const float* __restrict__ mask, const float* __restrict__ elem,
    const float* __restrict__ chars, const u16* __restrict__ wsT,
    const u16* __restrict__ woutrT, const u16* __restrict__ qkv0T,
    float* __restrict__ X, float* __restrict__ P, u16* __restrict__ QKVb)
{
    __shared__ __align__(16) u16 As[64 * 424];
    __shared__ float redS[64][4];
    const int LNOFF = 64 * 136;
    int tid = threadIdx.x;
    int row0 = blockIdx.x * 64;

    #pragma unroll
    for (int it = 0; it < 8; ++it) {
        int idx = tid + it * 256;
        int r = idx >> 5, c4 = idx & 31;
        f32x4v v = *(const f32x4v*)(elem + (size_t)(row0 + r) * 128 + c4 * 4);
        *(us4*)&As[r * 424 + c4 * 4] = pack4(v[0], v[1], v[2], v[3]);
    }
    #pragma unroll
    for (int it = 0; it < 16; ++it) {
        int idx = tid + it * 256;
        int r = idx >> 6, c4 = idx & 63;
        f32x4v v = *(const f32x4v*)(chars + (size_t)(row0 + r) * 256 + c4 * 4);
        *(us4*)&As[r * 424 + 128 + c4 * 4] = pack4(v[0], v[1], v[2], v[3]);
    }
    if (tid < 64) {
        int g = row0 + tid;
        As[tid * 424 + 384] = f2b(pos[g * 3]);
        As[tid * 424 + 385] = f2b(pos[g * 3 + 1]);
        As[tid * 424 + 386] = f2b(pos[g * 3 + 2]);
        As[tid * 424 + 387] = f2b(charge[g]);
        As[tid * 424 + 388] = f2b(mask[g]);
        for (int c = 389; c < 416; ++c) As[tid * 424 + c] = 0;
    }
    __syncthreads();

    int wv = tid >> 6, lane = tid & 63, quad = lane >> 4, l16 = lane & 15;
    int wm = (wv & 1) * 32, wn = (wv >> 1) * 64;
    f32x4v acc[2][4];
    #pragma unroll
    for (int i = 0; i < 2; ++i)
        #pragma unroll
        for (int j = 0; j < 4; ++j) acc[i][j] = (f32x4v){0.f, 0.f, 0.f, 0.f};

    #pragma unroll
    for (int kk = 0; kk < 13; ++kk) {
        short8 a0 = *(short8*)&As[(wm + l16) * 424 + kk * 32 + quad * 8];
        short8 a1 = *(short8*)&As[(wm + 16 + l16) * 424 + kk * 32 + quad * 8];
        #pragma unroll
        for (int nt = 0; nt < 4; ++nt) {
            short8 bw = *(const short8*)&wsT[(size_t)(wn + nt * 16 + l16) * 416 +
                                             kk * 32 + quad * 8];
            acc[0][nt] = __builtin_amdgcn_mfma_f32_16x16x32_bf16(a0, bw, acc[0][nt], 0, 0, 0);
            acc[1][nt] = __builtin_amdgcn_mfma_f32_16x16x32_bf16(a1, bw, acc[1][nt], 0, 0, 0);
        }
    }
    __syncthreads();

    #pragma unroll
    for (int mt = 0; mt < 2; ++mt) {
        #pragma unroll
        for (int r = 0; r < 4; ++r) {
            int lrow = wm + mt * 16 + quad * 4 + r;
            int row = row0 + lrow;
            float s = 0.f, ss = 0.f;
            #pragma unroll
            for (int nt = 0; nt < 4; ++nt) {
                float v = acc[mt][nt][r];
                int col = wn + nt * 16 + l16;
                X[(size_t)row * DS + col] = v;
                As[lrow * 136 + col] = f2b(fmaxf(v, 0.f));
                s += v; ss += v * v;
            }
            s  = sum16_dpp(s);
            ss = sum16_dpp(ss);
            if (l16 == 0) {
                redS[lrow][(wv >> 1) * 2]     = s;
                redS[lrow][(wv >> 1) * 2 + 1] = ss;
            }
        }
    }
    __syncthreads();

    #pragma unroll
    for (int mt = 0; mt < 2; ++mt)
        #pragma unroll
        for (int r = 0; r < 4; ++r) {
            int lrow = wm + mt * 16 + quad * 4 + r;
            f32x4v rv = *(f32x4v*)&redS[lrow][0];
            float s = rv[0] + rv[2], ss = rv[1] + rv[3];
            float m = s * (1.f / 128.f);
            float var = ss * (1.f / 128.f) - m * m;
            float rs = __builtin_amdgcn_rsqf(var + 1e-5f);
            #pragma unroll
            for (int nt = 0; nt < 4; ++nt) {
                int col = wn + nt * 16 + l16;
                As[LNOFF + lrow * 136 + col] = f2b((acc[mt][nt][r] - m) * rs);
            }
        }

    {
        f32x4v pacc[2];
        pacc[0] = (f32x4v){0.f, 0.f, 0.f, 0.f};
        pacc[1] = (f32x4v){0.f, 0.f, 0.f, 0.f};
        #pragma unroll
        for (int ks = 0; ks < 4; ++ks) {
            short8 a = *(short8*)&As[(wv * 16 + l16) * 136 + ks * 32 + quad * 8];
            #pragma unroll
            for (int nt = 0; nt < 2; ++nt) {
                short8 bw = *(const short8*)&woutrT[(size_t)(nt * 16 + l16) * 128 +
                                                    ks * 32 + quad * 8];
                pacc[nt] = __builtin_amdgcn_mfma_f32_16x16x32_bf16(a, bw, pacc[nt], 0, 0, 0);
            }
        }
        #pragma unroll
        for (int nt = 0; nt < 2; ++nt)
            #pragma unroll
            for (int r = 0; r < 4; ++r) {
                int row = row0 + wv * 16 + quad * 4 + r;
                P[(size_t)row * 32 + nt * 16 + l16] = pacc[nt][r];
            }
    }
    __syncthreads();

    for (int c = 0; c < 3; ++c) {
        int n0c = c * 128;
        f32x4v qa[2][4];
        #pragma unroll
        for (int i = 0; i < 2; ++i)
            #pragma unroll
            for (int j = 0; j < 4; ++j) qa[i][j] = (f32x4v){0.f, 0.f, 0.f, 0.f};
        #pragma unroll
        for (int ks = 0; ks < 4; ++ks) {
            short8 a0 = *(short8*)&As[LNOFF + (wm + l16) * 136 + ks * 32 + quad * 8];
            short8 a1 = *(short8*)&As[LNOFF + (wm + 16 + l16) * 136 + ks * 32 + quad * 8];
            #pragma unroll
            for (int nt = 0; nt < 4; ++nt) {
                short8 bw = *(const short8*)&qkv0T[(size_t)(n0c + wn + nt * 16 + l16) * 128 +
                                                   ks * 32 + quad * 8];
                qa[0][nt] = __builtin_amdgcn_mfma_f32_16x16x32_bf16(a0, bw, qa[0][nt], 0, 0, 0);
                qa[1][nt] = __builtin_amdgcn_mfma_f32_16x16x32_bf16(a1, bw, qa[1][nt], 0, 0, 0);
            }
        }
        #pragma unroll
        for (int mt = 0; mt < 2; ++mt)
            #pragma unroll
            for (int nt = 0; nt < 4; ++nt)
                #pragma unroll
                for (int r = 0; r < 4; ++r) {
                    int row = row0 + wm + mt * 16 + quad * 4 + r;
                    int col = n0c + wn + nt * 16 + l16;
                    QKVb[(size_t)row * 384 + col] = f2b(qa[mt][nt][r]);
                }
    }
}

// ---------------------------------------------------------------------------
// Bias kernel (unchanged).
// ---------------------------------------------------------------------------
__global__ __launch_bounds__(256) void bias_kernel(
    const float* __restrict__ pos, const int* __restrict__ uid,
    const float* __restrict__ P, const float* __restrict__ Wpair,
    const u16* __restrict__ w1T32, const u16* __restrict__ wcatT,
    u16* __restrict__ BIASb)
{
    __shared__ __align__(16) float posjS[128][4];
    __shared__ __align__(16) u16 lpS[4][16 * 24];
    __shared__ __align__(16) u16 A2S[4][16 * 104];

    int tid = threadIdx.x;
    int b  = blockIdx.x >> 11;
    int w  = (blockIdx.x >> 4) & 127;
    int qg = blockIdx.x & 15;

    if (tid < 128) {
        int r = tid;
        int jk = w * QW + r - PADW;
        bool valid = (jk >= 0) && (jk < N_);
        int gk = b * N_ + jk;
        float x = 0.f, y = 0.f, zz = 0.f; int u = 0;
        if (valid) { x = pos[gk * 3]; y = pos[gk * 3 + 1]; zz = pos[gk * 3 + 2]; u = uid[gk]; }
        posjS[r][0] = x; posjS[r][1] = y; posjS[r][2] = zz;
        ((int*)posjS[r])[3] = u;
    }

    int wv = tid >> 6, lane = tid & 63, quad = lane >> 4, l16 = lane & 15;
    int cl = lane >> 2, cg = lane & 3;
    int q = qg * 4 + wv;
    int gq = b * N_ + w * QW + q;

    float xi = pos[gq * 3], yi = pos[gq * 3 + 1], zi = pos[gq * 3 + 2];
    int ui = uid[gq];
    f32x4v pi4 = *(const f32x4v*)(P + (size_t)gq * 32 + cg * 4);
    f32x4v wp[5];
    #pragma unroll
    for (int f = 0; f < 5; ++f)
        wp[f] = *(const f32x4v*)(Wpair + f * 16 + cg * 4);
    short8 w1f[4], wcat[3];
    #pragma unroll
    for (int nt = 0; nt < 4; ++nt)
        w1f[nt] = *(const short8*)&w1T32[(nt * 16 + l16) * 32 + quad * 8];
    #pragma unroll
    for (int ks = 0; ks < 3; ++ks)
        wcat[ks] = *(const short8*)&wcatT[l16 * 96 + ks * 32 + quad * 8];

    f32x4v pjv[8];
    #pragma unroll
    for (int t = 0; t < 8; ++t) {
        int jk = w * QW + t * 16 + cl - PADW;
        bool valid = (jk >= 0) && (jk < N_);
        int gk = b * N_ + jk;
        f32x4v v = (f32x4v){0.f, 0.f, 0.f, 0.f};
        if (valid) v = *(const f32x4v*)(P + (size_t)gk * 32 + 16 + cg * 4);
        pjv[t] = v;
    }

    *(us4*)&A2S[wv][l16 * 104 + 80 + quad * 4] = (us4){0, 0, 0, 0};
    __syncthreads();

    size_t bbase = ((size_t)(b * NWIN + w) * HEADS) * (QW * KW);
    const short8 zero8 = (short8){0, 0, 0, 0, 0, 0, 0, 0};

    #pragma unroll 2
    for (int t = 0; t < 8; ++t) {
        int kk1 = t * 16 + cl;
        f32x4v pj4 = *(const f32x4v*)&posjS[kk1][0];
        float xj = pj4[0], yj = pj4[1], zj = pj4[2];
        int uj = __float_as_int(pj4[3]);
        float dx = xi - xj, dy = yi - yj, dz = zi - zj;
        float inv = __builtin_amdgcn_rcpf(1.f + dx * dx + dy * dy + dz * dz);
        float bf = (ui == uj) ? 1.f : 0.f;
        float pr[4];
        #pragma unroll
        for (int j = 0; j < 4; ++j) {
            float s = fmaf(dx, wp[0][j], fmaf(dy, wp[1][j],
                      fmaf(dz, wp[2][j], fmaf(inv, wp[3][j], wp[4][j]))));
            pr[j] = fmaf(bf, s, pi4[j] + pjv[t][j]);
        }
        float sum = pr[0] + pr[1] + pr[2] + pr[3];
        sum = sum4_dpp(sum);
        float m = sum * (1.f / 16.f);
        float d0 = pr[0] - m, d1 = pr[1] - m, d2 = pr[2] - m, d3 = pr[3] - m;
        float vs = d0 * d0 + d1 * d1 + d2 * d2 + d3 * d3;
        vs = sum4_dpp(vs);
        float rstd = __builtin_amdgcn_rsqf(vs * (1.f / 16.f) + 1e-5f);
        *(us4*)&lpS[wv][cl * 24 + cg * 4] =
            pack4(d0 * rstd, d1 * rstd, d2 * rstd, d3 * rstd);
        *(us4*)&A2S[wv][cl * 104 + cg * 4] = pack4(pr[0], pr[1], pr[2], pr[3]);

        short8 blp = zero8;
        if (quad < 2) blp = *(short8*)&lpS[wv][l16 * 24 + quad * 8];
        #pragma unroll
        for (int nt = 0; nt < 4; ++nt) {
            f32x4v z4 = (f32x4v){0.f, 0.f, 0.f, 0.f};
            z4 = __builtin_amdgcn_mfma_f32_16x16x32_bf16(w1f[nt], blp, z4, 0, 0, 0);
            *(us4*)&A2S[wv][l16 * 104 + 16 + nt * 16 + quad * 4] =
                pack4_relu(z4[0], z4[1], z4[2], z4[3]);
        }
        f32x4v acc = (f32x4v){0.f, 0.f, 0.f, 0.f};
        #pragma unroll
        for (int ks = 0; ks < 3; ++ks) {
            short8 a2 = *(short8*)&A2S[wv][l16 * 104 + ks * 32 + quad * 8];
            acc = __builtin_amdgcn_mfma_f32_16x16x32_bf16(a2, wcat[ks], acc, 0, 0, 0);
        }
        if (l16 < 4) {
            *(us4*)&BIASb[bbase + (size_t)l16 * (QW * KW) + q * KW +
                          t * 16 + quad * 4] = pack4(acc[0], acc[1], acc[2], acc[3]);
        }
    }
}

// ---------------------------------------------------------------------------
// wo_ff_fused<LAST> r19: 512-thread blocks, 8 waves, 16 rows/block.
// r2-r6 established: aggregate throughput = resident_waves x fixed
// per-wave rate (4 interventions on per-wave MLP all null; occupancy
// drops always cost proportionally).  r3's 37% occupancy was GRID-limited
// (1024 blocks x 4 waves = 16 waves/CU cap).  This version keeps grid
// 1024 but 8 waves/block -> 32 waves/CU cap (100%), LDS ~22KB (4
// blocks/CU fit), per-wave work halved (16-col slices for DS phases,
// 64 FF1 cols, 48 aux cols = 48 MFMAs/wave).  Per-wave state kept tiny
// so VGPR <= 64 (8 waves/SIMD).
// ---------------------------------------------------------------------------
template <bool LAST>
__global__ __launch_bounds__(512) void wo_ff_fused(
    const u16* __restrict__ Ob, const u16* __restrict__ woT,
    const u16* __restrict__ w1T, const u16* __restrict__ w2T,
    const u16* __restrict__ auxT, float* __restrict__ X,
    u16* __restrict__ OutB)
{
    __shared__ __align__(16) u16 As[16 * 136];    // 4.25 KB
    __shared__ __align__(16) u16 Hs[16 * 520];    // 16.25 KB
    __shared__ __align__(16) float redS[16][16];  // 1 KB
    int tid = threadIdx.x;
    int row0 = blockIdx.x * 16;
    int wv = tid >> 6, lane = tid & 63, quad = lane >> 4, l16 = lane & 15;
    int wn = wv * 16;

    if (tid < 256) {  // stage Ob tile: 16 x 128, short8 per thread
        int r = tid >> 4, c8 = tid & 15;
        *(short8*)&As[r * 136 + c8 * 8] =
            *(const short8*)&Ob[(size_t)(row0 + r) * 128 + c8 * 8];
    }
    __syncthreads();

    // ---- Wo GEMM: wave owns 16 output cols (wn..wn+15) ----
    f32x4v acc = (f32x4v){0.f, 0.f, 0.f, 0.f};
    #pragma unroll
    for (int ks = 0; ks < 4; ++ks) {
        short8 a = *(short8*)&As[l16 * 136 + ks * 32 + quad * 8];
        short8 b = *(const short8*)&woT[(size_t)(wn + l16) * 128 + ks * 32 + quad * 8];
        acc = __builtin_amdgcn_mfma_f32_16x16x32_bf16(a, b, acc, 0, 0, 0);
    }

    // ---- residual + LN1 partials (8 waves x {s,ss} per row) ----
    #pragma unroll
    for (int r = 0; r < 4; ++r) {
        int lrow = quad * 4 + r;
        float v = acc[r] + X[(size_t)(row0 + lrow) * DS + wn + l16];
        acc[r] = v;
        float s  = sum16_dpp(v);
        float ss = sum16_dpp(v * v);
        if (l16 == 0) {
            redS[lrow][wv * 2]     = s;
            redS[lrow][wv * 2 + 1] = ss;
        }
    }
    __syncthreads();

    #pragma unroll
    for (int r = 0; r < 4; ++r) {
        int lrow = quad * 4 + r;
        f32x4v a0 = *(f32x4v*)&redS[lrow][0];
        f32x4v a1 = *(f32x4v*)&redS[lrow][4];
        f32x4v a2 = *(f32x4v*)&redS[lrow][8];
        f32x4v a3 = *(f32x4v*)&redS[lrow][12];
        float s  = a0[0] + a0[2] + a1[0] + a1[2] + a2[0] + a2[2] + a3[0] + a3[2];
        float ss = a0[1] + a0[3] + a1[1] + a1[3] + a2[1] + a2[3] + a3[1] + a3[3];
        float m = s * (1.f / 128.f);
        float var = ss * (1.f / 128.f) - m * m;
        float rs = __builtin_amdgcn_rsqf(var + 1e-5f);
        As[lrow * 136 + wn + l16] = f2b((acc[r] - m) * rs);
    }
    __syncthreads();

    // ---- FF1: wave owns 64 H-cols (wv*64 .. +63) ----
    {
        short8 brow[4];
        #pragma unroll
        for (int ks = 0; ks < 4; ++ks)
            brow[ks] = *(short8*)&As[l16 * 136 + ks * 32 + quad * 8];
        #pragma unroll
        for (int mt = 0; mt < 4; ++mt) {
            int j0 = wv * 64 + mt * 16;
            f32x4v c0 = (f32x4v){0.f, 0.f, 0.f, 0.f};
            #pragma unroll
            for (int ks = 0; ks < 4; ++ks) {
                short8 aw = *(const short8*)&w1T[(size_t)(j0 + l16) * 128 +
                                                 ks * 32 + quad * 8];
                c0 = __builtin_amdgcn_mfma_f32_16x16x32_bf16(aw, brow[ks], c0, 0, 0, 0);
            }
            *(us4*)&Hs[l16 * 520 + j0 + quad * 4] =
                pack4_relu(c0[0], c0[1], c0[2], c0[3]);
        }
    }
    __syncthreads();

    // ---- FF2: wave owns 16 output cols over K=512 ----
    f32x4v acc2 = (f32x4v){0.f, 0.f, 0.f, 0.f};
    #pragma unroll
    for (int ks = 0; ks < 16; ++ks) {
        short8 a = *(short8*)&Hs[l16 * 520 + ks * 32 + quad * 8];
        short8 b = *(const short8*)&w2T[(size_t)(wn + l16) * 512 + ks * 32 + quad * 8];
        acc2 = __builtin_amdgcn_mfma_f32_16x16x32_bf16(a, b, acc2, 0, 0, 0);
    }

    // ---- residual2 (+X write unless LAST) + LN2 partials ----
    #pragma unroll
    for (int r = 0; r < 4; ++r) {
        int lrow = quad * 4 + r;
        float v = acc2[r] + acc[r];
        acc2[r] = v;
        if (!LAST)
            X[(size_t)(row0 + lrow) * DS + wn + l16] = v;
        float s  = sum16_dpp(v);
        float ss = sum16_dpp(v * v);
        if (l16 == 0) {
            redS[lrow][wv * 2]     = s;
            redS[lrow][wv * 2 + 1] = ss;
        }
    }
    __syncthreads();

    #pragma unroll
    for (int r = 0; r < 4; ++r) {
        int lrow = quad * 4 + r;
        float m = 0.f, rs = 1.f;
        if (!LAST) {
            f32x4v a0 = *(f32x4v*)&redS[lrow][0];
            f32x4v a1 = *(f32x4v*)&redS[lrow][4];
            f32x4v a2 = *(f32x4v*)&redS[lrow][8];
            f32x4v a3 = *(f32x4v*)&redS[lrow][12];
            float s  = a0[0] + a0[2] + a1[0] + a1[2] + a2[0] + a2[2] + a3[0] + a3[2];
            float ss = a0[1] + a0[3] + a1[1] + a1[3] + a2[1] + a2[3] + a3[1] + a3[3];
            m = s * (1.f / 128.f);
            float var = ss * (1.f / 128.f) - m * m;
            rs = __builtin_amdgcn_rsqf(var + 1e-5f);
        }
        As[lrow * 136 + wn + l16] = f2b(LAST ? acc2[r] : (acc2[r] - m) * rs);
    }
    __syncthreads();

    // ---- output GEMM: wave owns 48 cols (wv*48 .. +47) of 384 ----
    {
        short8 arow[4];
        #pragma unroll
        for (int ks = 0; ks < 4; ++ks)
            arow[ks] = *(short8*)&As[l16 * 136 + ks * 32 + quad * 8];
        #pragma unroll
        for (int t = 0; t < 3; ++t) {
            int col0 = wv * 48 + t * 16;
            f32x4v qa = (f32x4v){0.f, 0.f, 0.f, 0.f};
            #pragma unroll
            for (int ks = 0; ks < 4; ++ks) {
                short8 b = *(const short8*)&auxT[(size_t)(col0 + l16) * 128 +
                                                 ks * 32 + quad * 8];
                qa = __builtin_amdgcn_mfma_f32_16x16x32_bf16(arow[ks], b, qa, 0, 0, 0);
            }
            #pragma unroll
            for (int r = 0; r < 4; ++r) {
                float v = qa[r];
                if (LAST) v = fmaxf(v, 0.f);
                OutB[(size_t)(row0 + quad * 4 + r) * 384 + col0 + l16] = f2b(v);
            }
        }
    }
}

// ---------------------------------------------------------------------------
// Windowed attention v9 (r5 known-good, unchanged).
// ---------------------------------------------------------------------------
__global__ __launch_bounds__(256) void attn_kernel(
    const u16* __restrict__ QKV, const u16* __restrict__ BIASb,
    u16* __restrict__ O)
{
    __shared__ __align__(16) u16 sQ[64 * 40];    // 5 KB
    __shared__ __align__(16) u16 sK[128 * 40];   // 10 KB
    __shared__ __align__(16) u16 sVt[32 * 152];  // 9.5 KB
    __shared__ __align__(16) u16 sP[64 * 136];   // bias tile, then P (17 KB)

    int tid = threadIdx.x;
    int h = blockIdx.x & 3, w = (blockIdx.x >> 2) & 127, b = blockIdx.x >> 9;
    size_t rowbase = (size_t)b * N_ + w * QW;
    size_t bbase = ((size_t)(b * NWIN + w) * HEADS + h) * (QW * KW);
    const short8 zero8 = (short8){0, 0, 0, 0, 0, 0, 0, 0};
    const bool edge = (w == 0) || (w == NWIN - 1);

    {   // Q
        int r = tid >> 2, d8 = (tid & 3) * 8;
        *(short8*)&sQ[r * 40 + d8] =
            *(const short8*)&QKV[(rowbase + r) * 384 + h * DH + d8];
    }
    #pragma unroll
    for (int i = 0; i < 2; ++i) {  // K
        int idx = tid + i * 256;
        int r = idx >> 2, d8 = (idx & 3) * 8;
        int jk = w * QW + r - PADW;
        short8 v = zero8;
        if (jk >= 0 && jk < N_)
            v = *(const short8*)&QKV[((size_t)b * N_ + jk) * 384 + 128 + h * DH + d8];
        *(short8*)&sK[r * 40 + d8] = v;
    }
    {   // V transposed
        int kk = tid >> 1, d0 = (tid & 1) * 16;
        int jk = w * QW + kk - PADW;
        short8 v0 = zero8, v1 = zero8;
        if (jk >= 0 && jk < N_) {
            const u16* src = &QKV[((size_t)b * N_ + jk) * 384 + 256 + h * DH + d0];
            v0 = *(const short8*)src;
            v1 = *(const short8*)(src + 8);
        }
        #pragma unroll
        for (int j = 0; j < 8; ++j) {
            sVt[(d0 + j) * 152 + kk] = (u16)v0[j];
            sVt[(d0 + 8 + j) * 152 + kk] = (u16)v1[j];
        }
    }
    #pragma unroll
    for (int i = 0; i < 4; ++i) {  // bias tile -> sP
        int idx = tid + i * 256;
        int q = idx >> 4, c8 = idx & 15;
        *(short8*)&sP[q * 136 + c8 * 8] =
            *(const short8*)&BIASb[bbase + (size_t)q * KW + c8 * 8];
    }
    __syncthreads();  // the ONLY barrier

    int wv = tid >> 6, lane = tid & 63, quad = lane >> 4, l16 = lane & 15;
    const float scale = 0.17677669529663687f;  // 1/sqrt(32)

    // ---- QK^T: wave's 16 q rows x full 128 kk ----
    short8 aq = *(short8*)&sQ[(wv * 16 + l16) * 40 + quad * 8];
    float e[8][4];
    #pragma unroll
    for (int nt = 0; nt < 8; ++nt) {
        short8 bk = *(short8*)&sK[(nt * 16 + l16) * 40 + quad * 8];
        f32x4v acc = (f32x4v){0.f, 0.f, 0.f, 0.f};
        acc = __builtin_amdgcn_mfma_f32_16x16x32_bf16(aq, bk, acc, 0, 0, 0);
        int kk = nt * 16 + l16;
        float msk = 0.f;
        if (edge) {
            int jk = w * QW + kk - PADW;
            msk = (jk >= 0 && jk < N_) ? 0.f : -1e9f;
        }
        #pragma unroll
        for (int r = 0; r < 4; ++r) {
            int q = wv * 16 + quad * 4 + r;
            e[nt][r] = acc[r] * scale + b2f(sP[q * 136 + kk]) + msk;
        }
    }

    // ---- softmax fully within the wave (DPP row reductions) ----
    #pragma unroll
    for (int r = 0; r < 4; ++r) {
        float m = e[0][r];
        #pragma unroll
        for (int nt = 1; nt < 8; ++nt) m = fmaxf(m, e[nt][r]);
        m = max16_dpp(m);
        float s = 0.f;
        #pragma unroll
        for (int nt = 0; nt < 8; ++nt) {
            float ev = __expf(e[nt][r] - m);
            e[nt][r] = ev;
            s += ev;
        }
        s = sum16_dpp(s);
        float inv = __builtin_amdgcn_rcpf(s);
        #pragma unroll
        for (int nt = 0; nt < 8; ++nt) e[nt][r] *= inv;
    }

    // ---- write P into the wave's OWN sP rows (in-wave ordering only) ----
    #pragma unroll
    for (int nt = 0; nt < 8; ++nt) {
        int kk = nt * 16 + l16;
        #pragma unroll
        for (int r = 0; r < 4; ++r) {
            int q = wv * 16 + quad * 4 + r;
            sP[q * 136 + kk] = f2b(e[nt][r]);
        }
    }

    // ---- P @ V (reads the wave's own rows; lgkmcnt-ordered, no barrier) ----
    short8 ap[4];
    #pragma unroll
    for (int ks = 0; ks < 4; ++ks)
        ap[ks] = *(short8*)&sP[(wv * 16 + l16) * 136 + ks * 32 + quad * 8];
    #pragma unroll
    for (int nt = 0; nt < 2; ++nt) {
        f32x4v acc = (f32x4v){0.f, 0.f, 0.f, 0.f};
        #pragma unroll
        for (int ks = 0; ks < 4; ++ks) {
            short8 bv = *(short8*)&sVt[(nt * 16 + l16) * 152 + ks * 32 + quad * 8];
            acc = __builtin_amdgcn_mfma_f32_16x16x32_bf16(ap[ks], bv, acc, 0, 0, 0);
        }
        int d = nt * 16 + l16;
        #pragma unroll
        for (int r = 0; r < 4; ++r) {
            int q = wv * 16 + quad * 4 + r;
            O[(rowbase + q) * DS + h * DH + d] = f2b(acc[r]);
        }
    }
}

// ---------------------------------------------------------------------------
// Segment mean (unchanged).
// ---------------------------------------------------------------------------
__global__ __launch_bounds__(128) void seg_kernel(
    const u16* __restrict__ TOKb, const int* __restrict__ idx,
    float* __restrict__ out)
{
    int t = blockIdx.x & (NT - 1);
    int b = blockIdx.x >> 10;
    const int* id = idx + (size_t)b * N_;

    int lo = 0, hi = N_;
    while (lo < hi) { int mid = (lo + hi) >> 1; if (id[mid] < t) lo = mid + 1; else hi = mid; }
    int start = lo;
    hi = N_;
    while (lo < hi) { int mid = (lo + hi) >> 1; if (id[mid] < t + 1) lo = mid + 1; else hi = mid; }
    int end = lo;

    float inv = 1.f / fmaxf((float)(end - start), 1.f);
    if (threadIdx.x < 96) {
        int c4 = threadIdx.x * 4;
        f32x4v s = (f32x4v){0.f, 0.f, 0.f, 0.f};
        for (int r = start; r < end; ++r) {
            us4 v = *(const us4*)&TOKb[((size_t)b * N_ + r) * DT + c4];
            s[0] += b2f(v[0]); s[1] += b2f(v[1]);
            s[2] += b2f(v[2]); s[3] += b2f(v[3]);
        }
        s[0] *= inv; s[1] *= inv; s[2] *= inv; s[3] *= inv;
        *(f32x4v*)&out[((size_t)b * NT + t) * DT + c4] = s;
    }
}

// ---------------------------------------------------------------------------
extern "C" void kernel_launch(void* const* d_in, const int* in_sizes, int n_in,
                              void* d_out, int out_size, void* d_ws, size_t ws_size,
                              hipStream_t stream)
{
    const float* ref_pos    = (const float*)d_in[0];
    const float* ref_charge = (const float*)d_in[1];
    const float* ref_mask   = (const float*)d_in[2];
    const float* ref_elem   = (const float*)d_in[3];
    const float* ref_chars  = (const float*)d_in[4];
    const float* W_single   = (const float*)d_in[5];
    const float* W_pair     = (const float*)d_in[6];
    const float* W_outer    = (const float*)d_in[7];
    const float* Wp_ff1     = (const float*)d_in[8];
    const float* Wp_ff2     = (const float*)d_in[9];
    const float* Wq         = (const float*)d_in[10];
    const float* Wk         = (const float*)d_in[11];
    const float* Wv         = (const float*)d_in[12];
    const float* Wo         = (const float*)d_in[13];
    const float* Wb         = (const float*)d_in[14];
    const float* Wff1       = (const float*)d_in[15];
    const float* Wff2       = (const float*)d_in[16];
    const float* W_out      = (const float*)d_in[17];
    const int*   uid        = (const int*)d_in[18];
    const int*   a2t        = (const int*)d_in[19];
    float* out = (float*)d_out;

    const size_t ROWS = (size_t)B_ * N_;  // 16384
    float* ws = (float*)d_ws;
    float* X    = ws;
    float* P    = X + ROWS * DS;
    u16* QKVb   = (u16*)(P + ROWS * 32);
    u16* Ob     = QKVb + ROWS * 384;
    u16* FFb    = Ob + ROWS * DS;          // unused (layout stability)
    u16* BIASb  = FFb + ROWS * 512;
    u16* TOKb   = BIASb + (size_t)B_ * NWIN * HEADS * QW * KW;
    u16* LNb    = TOKb + ROWS * DT;        // unused
    u16* qkvT   = LNb + ROWS * DS;
    u16* woT    = qkvT + 3 * 384 * 128;
    u16* ff1T   = woT + 3 * 128 * 128;
    u16* ff2T   = ff1T + 3 * 512 * 128;
    u16* woutT  = ff2T + 3 * 128 * 512;
    u16* w1T32  = woutT + 384 * 128;
    u16* wcatT  = w1T32 + 64 * 32;
    u16* wsT    = wcatT + 16 * 96;
    u16* woutrT = wsT + 128 * 416;

    convw_kernel<<<768, 256, 0, stream>>>(Wq, Wk, Wv, Wo, Wff1, Wff2, W_out,
                                          Wp_ff1, Wp_ff2, Wb, W_single, W_outer,
                                          qkvT, woT, ff1T, ff2T, woutT,
                                          w1T32, wcatT, wsT, woutrT);
    embed_gemm<<<ROWS / 64, 256, 0, stream>>>(ref_pos, ref_charge, ref_mask,
                                              ref_elem, ref_chars, wsT, woutrT,
                                              qkvT, X, P, QKVb);
    bias_kernel<<<4096, 256, 0, stream>>>(ref_pos, uid, P, W_pair,
                                          w1T32, wcatT, BIASb);

    for (int l = 0; l < DEPTH; ++l) {
        attn_kernel<<<B_ * NWIN * HEADS, 256, 0, stream>>>(QKVb, BIASb, Ob);
        if (l < DEPTH - 1) {
            wo_ff_fused<false><<<ROWS / 16, 512, 0, stream>>>(
                Ob, woT + (size_t)l * 128 * 128,
                ff1T + (size_t)l * 512 * 128, ff2T + (size_t)l * 128 * 512,
                qkvT + (size_t)(l + 1) * 384 * 128, X, QKVb);
        } else {
            wo_ff_fused<true><<<ROWS / 16, 512, 0, stream>>>(
                Ob, woT + (size_t)l * 128 * 128,
                ff1T + (size_t)l * 512 * 128, ff2T + (size_t)l * 128 * 512,
                woutT, X, TOKb);
        }
    }

    seg_kernel<<<B_ * NT, 128, 0, stream>>>(TOKb, a2t, out);
}

// Round 8
// 349.897 us; speedup vs baseline: 1.3544x; 1.0681x over previous
//
#include <hip/hip_runtime.h>
#include <hip/hip_bf16.h>

#define QW 64
#define KW 128
#define PADW 32
#define DEPTH 3
#define HEADS 4
#define B_ 2
#define N_ 8192
#define DS 128
#define DP 16
#define DT 384
#define NT 1024
#define NWIN (N_ / QW)   // 128
#define DH (DS / HEADS)  // 32

typedef unsigned short u16;
typedef __attribute__((ext_vector_type(8))) short short8;
typedef __attribute__((ext_vector_type(4))) float f32x4v;
typedef __attribute__((ext_vector_type(4))) unsigned short us4;
typedef __attribute__((ext_vector_type(2))) short s16x2;

__device__ __forceinline__ u16 f2b(float x) {
    union { float f; unsigned u; } v; v.f = x;
    unsigned r = v.u + 0x7fffu + ((v.u >> 16) & 1u);
    return (u16)(r >> 16);
}
__device__ __forceinline__ float b2f(u16 h) {
    union { unsigned u; float f; } v; v.u = ((unsigned)h) << 16; return v.f;
}
__device__ __forceinline__ unsigned f2b2(float a, float b) {
    __hip_bfloat162 h = __float22bfloat162_rn(make_float2(a, b));
    union { __hip_bfloat162 h; unsigned u; } c; c.h = h; return c.u;
}
__device__ __forceinline__ us4 pack4(float a, float b, float c, float d) {
    union { us4 v; unsigned u[2]; } o;
    o.u[0] = f2b2(a, b);
    o.u[1] = f2b2(c, d);
    return o.v;
}
// relu AFTER packing: bf16 is sign-ordered vs 0 as int16, so packed
// v_pk_max_i16 against 0 == relu on both halves.
__device__ __forceinline__ us4 pack4_relu(float a, float b, float c, float d) {
    union { us4 v; s16x2 s[2]; unsigned u[2]; } o;
    o.u[0] = f2b2(a, b);
    o.u[1] = f2b2(c, d);
    o.s[0] = __builtin_elementwise_max(o.s[0], (s16x2)0);
    o.s[1] = __builtin_elementwise_max(o.s[1], (s16x2)0);
    return o.v;
}

// ---------------------------------------------------------------------------
// DPP cross-lane reductions (VALU, no LDS pipe).
// ---------------------------------------------------------------------------
template <int CTRL>
__device__ __forceinline__ float fdpp(float x) {
    int r = __builtin_amdgcn_update_dpp(0, __builtin_bit_cast(int, x),
                                        CTRL, 0xF, 0xF, true);
    return __builtin_bit_cast(float, r);
}
__device__ __forceinline__ float sum4_dpp(float x) {
    x += fdpp<0xB1>(x);
    x += fdpp<0x4E>(x);
    return x;
}
__device__ __forceinline__ float sum16_dpp(float x) {
    x += fdpp<0xB1>(x);
    x += fdpp<0x4E>(x);
    x += fdpp<0x124>(x);
    x += fdpp<0x128>(x);
    return x;
}
__device__ __forceinline__ float max16_dpp(float x) {
    x = fmaxf(x, fdpp<0xB1>(x));
    x = fmaxf(x, fdpp<0x4E>(x));
    x = fmaxf(x, fdpp<0x124>(x));
    x = fmaxf(x, fdpp<0x128>(x));
    return x;
}

// ---------------------------------------------------------------------------
// Weight prep (unchanged).
// ---------------------------------------------------------------------------
__global__ __launch_bounds__(256) void convw_kernel(
    const float* __restrict__ Wq, const float* __restrict__ Wk,
    const float* __restrict__ Wv, const float* __restrict__ Wo,
    const float* __restrict__ Wff1, const float* __restrict__ Wff2,
    const float* __restrict__ Wout, const float* __restrict__ Wpff1,
    const float* __restrict__ Wpff2, const float* __restrict__ Wb,
    const float* __restrict__ Wsingle, const float* __restrict__ Wouter,
    u16* __restrict__ qkvT, u16* __restrict__ woT, u16* __restrict__ ff1T,
    u16* __restrict__ ff2T, u16* __restrict__ woutT,
    u16* __restrict__ w1T32, u16* __restrict__ wcatT,
    u16* __restrict__ wsT, u16* __restrict__ woutrT)
{
    int idx = blockIdx.x * 256 + threadIdx.x;
    if (idx < 3 * 384 * 128) {
        int l = idx / (384 * 128), r = idx % (384 * 128);
        int n = r / 128, k = r % 128;
        const float* W = (n < 128) ? Wq : (n < 256) ? Wk : Wv;
        qkvT[idx] = f2b(W[(size_t)l * 16384 + k * 128 + (n & 127)]);
    }
    if (idx < 3 * 128 * 128) {
        int l = idx / 16384, r = idx % 16384;
        int n = r / 128, k = r % 128;
        woT[idx] = f2b(Wo[(size_t)l * 16384 + k * 128 + n]);
    }
    if (idx < 3 * 512 * 128) {
        int l = idx / 65536, r = idx % 65536;
        int n = r / 128, k = r % 128;
        ff1T[idx] = f2b(Wff1[(size_t)l * 65536 + k * 512 + n]);
    }
    if (idx < 3 * 128 * 512) {
        int l = idx / 65536, r = idx % 65536;
        int n = r / 512, k = r % 512;
        ff2T[idx] = f2b(Wff2[(size_t)l * 65536 + k * 128 + n]);
    }
    if (idx < 384 * 128) {
        int n = idx / 128, k = idx % 128;
        woutT[idx] = f2b(Wout[(size_t)k * 384 + n]);
    }
    if (idx < 64 * 32) {
        int n = idx >> 5, k = idx & 31;
        w1T32[idx] = (k < 16) ? f2b(Wpff1[k * 64 + n]) : (u16)0;
    }
    if (idx < 16 * 96) {
        int h = idx / 96, k = idx % 96;
        float s = 0.f;
        if (h < 4) {
            if (k < 16) s = Wb[k * 4 + h];
            else if (k < 80) {
                int j = k - 16;
                for (int c = 0; c < 16; ++c) s += Wpff2[j * 16 + c] * Wb[c * 4 + h];
            }
        }
        wcatT[idx] = f2b(s);
    }
    if (idx < 128 * 416) {
        int n = idx / 416, k = idx % 416;
        float v = 0.f;
        if (k < 128)       v = Wsingle[(5 + k) * 128 + n];
        else if (k < 384)  v = Wsingle[(133 + k - 128) * 128 + n];
        else if (k < 387)  v = Wsingle[(k - 384) * 128 + n];
        else if (k == 387) v = Wsingle[3 * 128 + n];
        else if (k == 388) v = Wsingle[4 * 128 + n];
        wsT[idx] = f2b(v);
    }
    if (idx < 32 * 128) {
        int n = idx >> 7, k = idx & 127;
        woutrT[idx] = f2b(Wouter[k * 32 + n]);
    }
}

// ---------------------------------------------------------------------------
// Embed GEMM + fused LN + P-GEMM + layer-0 QKV GEMM (unchanged).
// ---------------------------------------------------------------------------
__global__ __launch_bounds__(256) void embed_gemm(
    const float* __restrict__ pos, const float* __restrict__ charge,
    const float* __restrict__ mask, const float* __restrict__ elem,
    const float* __restrict__ chars, const u16* __restrict__ wsT,
    const u16* __restrict__ woutrT, const u16* __restrict__ qkv0T,
    float* __restrict__ X, float* __restrict__ P, u16* __restrict__ QKVb)
{
    __shared__ __align__(16) u16 As[64 * 424];
    __shared__ float redS[64][4];
    const int LNOFF = 64 * 136;
    int tid = threadIdx.x;
    int row0 = blockIdx.x * 64;

    #pragma unroll
    for (int it = 0; it < 8; ++it) {
        int idx = tid + it * 256;
        int r = idx >> 5, c4 = idx & 31;
        f32x4v v = *(const f32x4v*)(elem + (size_t)(row0 + r) * 128 + c4 * 4);
        *(us4*)&As[r * 424 + c4 * 4] = pack4(v[0], v[1], v[2], v[3]);
    }
    #pragma unroll
    for (int it = 0; it < 16; ++it) {
        int idx = tid + it * 256;
        int r = idx >> 6, c4 = idx & 63;
        f32x4v v = *(const f32x4v*)(chars + (size_t)(row0 + r) * 256 + c4 * 4);
        *(us4*)&As[r * 424 + 128 + c4 * 4] = pack4(v[0], v[1], v[2], v[3]);
    }
    if (tid < 64) {
        int g = row0 + tid;
        As[tid * 424 + 384] = f2b(pos[g * 3]);
        As[tid * 424 + 385] = f2b(pos[g * 3 + 1]);
        As[tid * 424 + 386] = f2b(pos[g * 3 + 2]);
        As[tid * 424 + 387] = f2b(charge[g]);
        As[tid * 424 + 388] = f2b(mask[g]);
        for (int c = 389; c < 416; ++c) As[tid * 424 + c] = 0;
    }
    __syncthreads();

    int wv = tid >> 6, lane = tid & 63, quad = lane >> 4, l16 = lane & 15;
    int wm = (wv & 1) * 32, wn = (wv >> 1) * 64;
    f32x4v acc[2][4];
    #pragma unroll
    for (int i = 0; i < 2; ++i)
        #pragma unroll
        for (int j = 0; j < 4; ++j) acc[i][j] = (f32x4v){0.f, 0.f, 0.f, 0.f};

    #pragma unroll
    for (int kk = 0; kk < 13; ++kk) {
        short8 a0 = *(short8*)&As[(wm + l16) * 424 + kk * 32 + quad * 8];
        short8 a1 = *(short8*)&As[(wm + 16 + l16) * 424 + kk * 32 + quad * 8];
        #pragma unroll
        for (int nt = 0; nt < 4; ++nt) {
            short8 bw = *(const short8*)&wsT[(size_t)(wn + nt * 16 + l16) * 416 +
                                             kk * 32 + quad * 8];
            acc[0][nt] = __builtin_amdgcn_mfma_f32_16x16x32_bf16(a0, bw, acc[0][nt], 0, 0, 0);
            acc[1][nt] = __builtin_amdgcn_mfma_f32_16x16x32_bf16(a1, bw, acc[1][nt], 0, 0, 0);
        }
    }
    __syncthreads();

    #pragma unroll
    for (int mt = 0; mt < 2; ++mt) {
        #pragma unroll
        for (int r = 0; r < 4; ++r) {
            int lrow = wm + mt * 16 + quad * 4 + r;
            int row = row0 + lrow;
            float s = 0.f, ss = 0.f;
            #pragma unroll
            for (int nt = 0; nt < 4; ++nt) {
                float v = acc[mt][nt][r];
                int col = wn + nt * 16 + l16;
                X[(size_t)row * DS + col] = v;
                As[lrow * 136 + col] = f2b(fmaxf(v, 0.f));
                s += v; ss += v * v;
            }
            s  = sum16_dpp(s);
            ss = sum16_dpp(ss);
            if (l16 == 0) {
                redS[lrow][(wv >> 1) * 2]     = s;
                redS[lrow][(wv >> 1) * 2 + 1] = ss;
            }
        }
    }
    __syncthreads();

    #pragma unroll
    for (int mt = 0; mt < 2; ++mt)
        #pragma unroll
        for (int r = 0; r < 4; ++r) {
            int lrow = wm + mt * 16 + quad * 4 + r;
            f32x4v rv = *(f32x4v*)&redS[lrow][0];
            float s = rv[0] + rv[2], ss = rv[1] + rv[3];
            float m = s * (1.f / 128.f);
            float var = ss * (1.f / 128.f) - m * m;
            float rs = __builtin_amdgcn_rsqf(var + 1e-5f);
            #pragma unroll
            for (int nt = 0; nt < 4; ++nt) {
                int col = wn + nt * 16 + l16;
                As[LNOFF + lrow * 136 + col] = f2b((acc[mt][nt][r] - m) * rs);
            }
        }

    {
        f32x4v pacc[2];
        pacc[0] = (f32x4v){0.f, 0.f, 0.f, 0.f};
        pacc[1] = (f32x4v){0.f, 0.f, 0.f, 0.f};
        #pragma unroll
        for (int ks = 0; ks < 4; ++ks) {
            short8 a = *(short8*)&As[(wv * 16 + l16) * 136 + ks * 32 + quad * 8];
            #pragma unroll
            for (int nt = 0; nt < 2; ++nt) {
                short8 bw = *(const short8*)&woutrT[(size_t)(nt * 16 + l16) * 128 +
                                                    ks * 32 + quad * 8];
                pacc[nt] = __builtin_amdgcn_mfma_f32_16x16x32_bf16(a, bw, pacc[nt], 0, 0, 0);
            }
        }
        #pragma unroll
        for (int nt = 0; nt < 2; ++nt)
            #pragma unroll
            for (int r = 0; r < 4; ++r) {
                int row = row0 + wv * 16 + quad * 4 + r;
                P[(size_t)row * 32 + nt * 16 + l16] = pacc[nt][r];
            }
    }
    __syncthreads();

    for (int c = 0; c < 3; ++c) {
        int n0c = c * 128;
        f32x4v qa[2][4];
        #pragma unroll
        for (int i = 0; i < 2; ++i)
            #pragma unroll
            for (int j = 0; j < 4; ++j) qa[i][j] = (f32x4v){0.f, 0.f, 0.f, 0.f};
        #pragma unroll
        for (int ks = 0; ks < 4; ++ks) {
            short8 a0 = *(short8*)&As[LNOFF + (wm + l16) * 136 + ks * 32 + quad * 8];
            short8 a1 = *(short8*)&As[LNOFF + (wm + 16 + l16) * 136 + ks * 32 + quad * 8];
            #pragma unroll
            for (int nt = 0; nt < 4; ++nt) {
                short8 bw = *(const short8*)&qkv0T[(size_t)(n0c + wn + nt * 16 + l16) * 128 +
                                                   ks * 32 + quad * 8];
                qa[0][nt] = __builtin_amdgcn_mfma_f32_16x16x32_bf16(a0, bw, qa[0][nt], 0, 0, 0);
                qa[1][nt] = __builtin_amdgcn_mfma_f32_16x16x32_bf16(a1, bw, qa[1][nt], 0, 0, 0);
            }
        }
        #pragma unroll
        for (int mt = 0; mt < 2; ++mt)
            #pragma unroll
            for (int nt = 0; nt < 4; ++nt)
                #pragma unroll
                for (int r = 0; r < 4; ++r) {
                    int row = row0 + wm + mt * 16 + quad * 4 + r;
                    int col = n0c + wn + nt * 16 + l16;
                    QKVb[(size_t)row * 384 + col] = f2b(qa[mt][nt][r]);
                }
    }
}

// ---------------------------------------------------------------------------
// Bias kernel (unchanged).
// ---------------------------------------------------------------------------
__global__ __launch_bounds__(256) void bias_kernel(
    const float* __restrict__ pos, const int* __restrict__ uid,
    const float* __restrict__ P, const float* __restrict__ Wpair,
    const u16* __restrict__ w1T32, const u16* __restrict__ wcatT,
    u16* __restrict__ BIASb)
{
    __shared__ __align__(16) float posjS[128][4];
    __shared__ __align__(16) u16 lpS[4][16 * 24];
    __shared__ __align__(16) u16 A2S[4][16 * 104];

    int tid = threadIdx.x;
    int b  = blockIdx.x >> 11;
    int w  = (blockIdx.x >> 4) & 127;
    int qg = blockIdx.x & 15;

    if (tid < 128) {
        int r = tid;
        int jk = w * QW + r - PADW;
        bool valid = (jk >= 0) && (jk < N_);
        int gk = b * N_ + jk;
        float x = 0.f, y = 0.f, zz = 0.f; int u = 0;
        if (valid) { x = pos[gk * 3]; y = pos[gk * 3 + 1]; zz = pos[gk * 3 + 2]; u = uid[gk]; }
        posjS[r][0] = x; posjS[r][1] = y; posjS[r][2] = zz;
        ((int*)posjS[r])[3] = u;
    }

    int wv = tid >> 6, lane = tid & 63, quad = lane >> 4, l16 = lane & 15;
    int cl = lane >> 2, cg = lane & 3;
    int q = qg * 4 + wv;
    int gq = b * N_ + w * QW + q;

    float xi = pos[gq * 3], yi = pos[gq * 3 + 1], zi = pos[gq * 3 + 2];
    int ui = uid[gq];
    f32x4v pi4 = *(const f32x4v*)(P + (size_t)gq * 32 + cg * 4);
    f32x4v wp[5];
    #pragma unroll
    for (int f = 0; f < 5; ++f)
        wp[f] = *(const f32x4v*)(Wpair + f * 16 + cg * 4);
    short8 w1f[4], wcat[3];
    #pragma unroll
    for (int nt = 0; nt < 4; ++nt)
        w1f[nt] = *(const short8*)&w1T32[(nt * 16 + l16) * 32 + quad * 8];
    #pragma unroll
    for (int ks = 0; ks < 3; ++ks)
        wcat[ks] = *(const short8*)&wcatT[l16 * 96 + ks * 32 + quad * 8];

    f32x4v pjv[8];
    #pragma unroll
    for (int t = 0; t < 8; ++t) {
        int jk = w * QW + t * 16 + cl - PADW;
        bool valid = (jk >= 0) && (jk < N_);
        int gk = b * N_ + jk;
        f32x4v v = (f32x4v){0.f, 0.f, 0.f, 0.f};
        if (valid) v = *(const f32x4v*)(P + (size_t)gk * 32 + 16 + cg * 4);
        pjv[t] = v;
    }

    *(us4*)&A2S[wv][l16 * 104 + 80 + quad * 4] = (us4){0, 0, 0, 0};
    __syncthreads();

    size_t bbase = ((size_t)(b * NWIN + w) * HEADS) * (QW * KW);
    const short8 zero8 = (short8){0, 0, 0, 0, 0, 0, 0, 0};

    #pragma unroll 2
    for (int t = 0; t < 8; ++t) {
        int kk1 = t * 16 + cl;
        f32x4v pj4 = *(const f32x4v*)&posjS[kk1][0];
        float xj = pj4[0], yj = pj4[1], zj = pj4[2];
        int uj = __float_as_int(pj4[3]);
        float dx = xi - xj, dy = yi - yj, dz = zi - zj;
        float inv = __builtin_amdgcn_rcpf(1.f + dx * dx + dy * dy + dz * dz);
        float bf = (ui == uj) ? 1.f : 0.f;
        float pr[4];
        #pragma unroll
        for (int j = 0; j < 4; ++j) {
            float s = fmaf(dx, wp[0][j], fmaf(dy, wp[1][j],
                      fmaf(dz, wp[2][j], fmaf(inv, wp[3][j], wp[4][j]))));
            pr[j] = fmaf(bf, s, pi4[j] + pjv[t][j]);
        }
        float sum = pr[0] + pr[1] + pr[2] + pr[3];
        sum = sum4_dpp(sum);
        float m = sum * (1.f / 16.f);
        float d0 = pr[0] - m, d1 = pr[1] - m, d2 = pr[2] - m, d3 = pr[3] - m;
        float vs = d0 * d0 + d1 * d1 + d2 * d2 + d3 * d3;
        vs = sum4_dpp(vs);
        float rstd = __builtin_amdgcn_rsqf(vs * (1.f / 16.f) + 1e-5f);
        *(us4*)&lpS[wv][cl * 24 + cg * 4] =
            pack4(d0 * rstd, d1 * rstd, d2 * rstd, d3 * rstd);
        *(us4*)&A2S[wv][cl * 104 + cg * 4] = pack4(pr[0], pr[1], pr[2], pr[3]);

        short8 blp = zero8;
        if (quad < 2) blp = *(short8*)&lpS[wv][l16 * 24 + quad * 8];
        #pragma unroll
        for (int nt = 0; nt < 4; ++nt) {
            f32x4v z4 = (f32x4v){0.f, 0.f, 0.f, 0.f};
            z4 = __builtin_amdgcn_mfma_f32_16x16x32_bf16(w1f[nt], blp, z4, 0, 0, 0);
            *(us4*)&A2S[wv][l16 * 104 + 16 + nt * 16 + quad * 4] =
                pack4_relu(z4[0], z4[1], z4[2], z4[3]);
        }
        f32x4v acc = (f32x4v){0.f, 0.f, 0.f, 0.f};
        #pragma unroll
        for (int ks = 0; ks < 3; ++ks) {
            short8 a2 = *(short8*)&A2S[wv][l16 * 104 + ks * 32 + quad * 8];
            acc = __builtin_amdgcn_mfma_f32_16x16x32_bf16(a2, wcat[ks], acc, 0, 0, 0);
        }
        if (l16 < 4) {
            *(us4*)&BIASb[bbase + (size_t)l16 * (QW * KW) + q * KW +
                          t * 16 + quad * 4] = pack4(acc[0], acc[1], acc[2], acc[3]);
        }
    }
}

// ---------------------------------------------------------------------------
// wo_ff_fused<LAST> r20: VERBATIM restore of the r2 (32-row, 512-block)
// version -- the best-total configuration.  r2->r7 totals show the 16-row
// variants cost ~16us globally (2x weight streaming evicts QKVb/BIASb
// from L2 between dispatches, taxing the following attn) even though
// their own dispatch duration is flat.
// ---------------------------------------------------------------------------
template <bool LAST>
__global__ __launch_bounds__(256) void wo_ff_fused(
    const u16* __restrict__ Ob, const u16* __restrict__ woT,
    const u16* __restrict__ w1T, const u16* __restrict__ w2T,
    const u16* __restrict__ auxT, float* __restrict__ X,
    u16* __restrict__ OutB)
{
    __shared__ __align__(16) u16 As[32 * 136];
    __shared__ __align__(16) u16 Hs[32 * 520];
    __shared__ float redS[32][4];
    int tid = threadIdx.x;
    int row0 = blockIdx.x * 32;
    int wv = tid >> 6, lane = tid & 63, quad = lane >> 4, l16 = lane & 15;
    int wm = (wv & 1) * 16, wn = (wv >> 1) * 64;

    #pragma unroll
    for (int it = 0; it < 2; ++it) {
        int idx = tid + it * 256;
        int r = idx >> 4, c8 = idx & 15;
        *(short8*)&As[r * 136 + c8 * 8] =
            *(const short8*)&Ob[(size_t)(row0 + r) * 128 + c8 * 8];
    }
    __syncthreads();

    f32x4v acc[4];
    #pragma unroll
    for (int j = 0; j < 4; ++j) acc[j] = (f32x4v){0.f, 0.f, 0.f, 0.f};
    #pragma unroll
    for (int ks = 0; ks < 4; ++ks) {
        short8 a = *(short8*)&As[(wm + l16) * 136 + ks * 32 + quad * 8];
        #pragma unroll
        for (int nt = 0; nt < 4; ++nt) {
            short8 b = *(const short8*)&woT[(size_t)(wn + nt * 16 + l16) * 128 +
                                            ks * 32 + quad * 8];
            acc[nt] = __builtin_amdgcn_mfma_f32_16x16x32_bf16(a, b, acc[nt], 0, 0, 0);
        }
    }
    __syncthreads();

    #pragma unroll
    for (int r = 0; r < 4; ++r) {
        int lrow = wm + quad * 4 + r;
        int row = row0 + lrow;
        float s = 0.f, ss = 0.f;
        #pragma unroll
        for (int nt = 0; nt < 4; ++nt) {
            int col = wn + nt * 16 + l16;
            float v = acc[nt][r] + X[(size_t)row * DS + col];
            acc[nt][r] = v;
            s += v; ss += v * v;
        }
        s  = sum16_dpp(s);
        ss = sum16_dpp(ss);
        if (l16 == 0) {
            redS[lrow][(wv >> 1) * 2]     = s;
            redS[lrow][(wv >> 1) * 2 + 1] = ss;
        }
    }
    __syncthreads();

    #pragma unroll
    for (int r = 0; r < 4; ++r) {
        int lrow = wm + quad * 4 + r;
        f32x4v rv = *(f32x4v*)&redS[lrow][0];
        float s = rv[0] + rv[2], ss = rv[1] + rv[3];
        float m = s * (1.f / 128.f);
        float var = ss * (1.f / 128.f) - m * m;
        float rs = __builtin_amdgcn_rsqf(var + 1e-5f);
        #pragma unroll
        for (int nt = 0; nt < 4; ++nt) {
            int col = wn + nt * 16 + l16;
            As[lrow * 136 + col] = f2b((acc[nt][r] - m) * rs);
        }
    }
    __syncthreads();

    {
        short8 brow[2][4];
        #pragma unroll
        for (int nt = 0; nt < 2; ++nt)
            #pragma unroll
            for (int ks = 0; ks < 4; ++ks)
                brow[nt][ks] = *(short8*)&As[(nt * 16 + l16) * 136 + ks * 32 + quad * 8];
        #pragma unroll
        for (int mt = 0; mt < 8; ++mt) {
            int j0 = wv * 128 + mt * 16;
            f32x4v c0 = (f32x4v){0.f, 0.f, 0.f, 0.f};
            f32x4v c1 = (f32x4v){0.f, 0.f, 0.f, 0.f};
            #pragma unroll
            for (int ks = 0; ks < 4; ++ks) {
                short8 aw = *(const short8*)&w1T[(size_t)(j0 + l16) * 128 +
                                                 ks * 32 + quad * 8];
                c0 = __builtin_amdgcn_mfma_f32_16x16x32_bf16(aw, brow[0][ks], c0, 0, 0, 0);
                c1 = __builtin_amdgcn_mfma_f32_16x16x32_bf16(aw, brow[1][ks], c1, 0, 0, 0);
            }
            *(us4*)&Hs[l16 * 520 + j0 + quad * 4] =
                pack4_relu(c0[0], c0[1], c0[2], c0[3]);
            *(us4*)&Hs[(16 + l16) * 520 + j0 + quad * 4] =
                pack4_relu(c1[0], c1[1], c1[2], c1[3]);
        }
    }
    __syncthreads();

    f32x4v acc2[4];
    #pragma unroll
    for (int j = 0; j < 4; ++j) acc2[j] = (f32x4v){0.f, 0.f, 0.f, 0.f};
    #pragma unroll
    for (int ks = 0; ks < 16; ++ks) {
        short8 a = *(short8*)&Hs[(wm + l16) * 520 + ks * 32 + quad * 8];
        #pragma unroll
        for (int nt = 0; nt < 4; ++nt) {
            short8 b = *(const short8*)&w2T[(size_t)(wn + nt * 16 + l16) * 512 +
                                            ks * 32 + quad * 8];
            acc2[nt] = __builtin_amdgcn_mfma_f32_16x16x32_bf16(a, b, acc2[nt], 0, 0, 0);
        }
    }

    #pragma unroll
    for (int r = 0; r < 4; ++r) {
        int lrow = wm + quad * 4 + r;
        int row = row0 + lrow;
        float s = 0.f, ss = 0.f;
        #pragma unroll
        for (int nt = 0; nt < 4; ++nt) {
            int col = wn + nt * 16 + l16;
            float v = acc2[nt][r] + acc[nt][r];
            acc2[nt][r] = v;
            X[(size_t)row * DS + col] = v;
            s += v; ss += v * v;
        }
        s  = sum16_dpp(s);
        ss = sum16_dpp(ss);
        if (l16 == 0) {
            redS[lrow][(wv >> 1) * 2]     = s;
            redS[lrow][(wv >> 1) * 2 + 1] = ss;
        }
    }
    __syncthreads();

    #pragma unroll
    for (int r = 0; r < 4; ++r) {
        int lrow = wm + quad * 4 + r;
        float m = 0.f, rs = 1.f;
        if (!LAST) {
            f32x4v rv = *(f32x4v*)&redS[lrow][0];
            float s = rv[0] + rv[2], ss = rv[1] + rv[3];
            m = s * (1.f / 128.f);
            float var = ss * (1.f / 128.f) - m * m;
            rs = __builtin_amdgcn_rsqf(var + 1e-5f);
        }
        #pragma unroll
        for (int nt = 0; nt < 4; ++nt) {
            int col = wn + nt * 16 + l16;
            float v = acc2[nt][r];
            As[lrow * 136 + col] = f2b(LAST ? v : (v - m) * rs);
        }
    }
    __syncthreads();

    for (int c = 0; c < 3; ++c) {
        int n0c = c * 128;
        f32x4v qa[4];
        #pragma unroll
        for (int j = 0; j < 4; ++j) qa[j] = (f32x4v){0.f, 0.f, 0.f, 0.f};
        #pragma unroll
        for (int ks = 0; ks < 4; ++ks) {
            short8 a = *(short8*)&As[(wm + l16) * 136 + ks * 32 + quad * 8];
            #pragma unroll
            for (int nt = 0; nt < 4; ++nt) {
                short8 b = *(const short8*)&auxT[(size_t)(n0c + wn + nt * 16 + l16) * 128 +
                                                 ks * 32 + quad * 8];
                qa[nt] = __builtin_amdgcn_mfma_f32_16x16x32_bf16(a, b, qa[nt], 0, 0, 0);
            }
        }
        #pragma unroll
        for (int nt = 0; nt < 4; ++nt)
            #pragma unroll
            for (int r = 0; r < 4; ++r) {
                int row = row0 + wm + quad * 4 + r;
                int col = n0c + wn + nt * 16 + l16;
                float v = qa[nt][r];
                if (LAST) v = fmaxf(v, 0.f);
                OutB[(size_t)row * 384 + col] = f2b(v);
            }
    }
}

// ---------------------------------------------------------------------------
// Windowed attention v10: SWAPPED QK^T -- mfma(K,Q) gives D[kk][q], so each
// lane's 4 accumulator regs hold 4 CONSECUTIVE kk for a FIXED q=wv*16+l16.
// Bias add becomes one 8B ds_read_b64 per kt (was 32 scalar reads/thread);
// P writeback becomes one 8B vector write per kt (was 32 scalar writes).
// Softmax: 32-value in-lane reduce + shfl_xor(16)+shfl_xor(32) cross-quad.
// PV unchanged.  + s_setprio around MFMA clusters (m191).
// ---------------------------------------------------------------------------
__global__ __launch_bounds__(256) void attn_kernel(
    const u16* __restrict__ QKV, const u16* __restrict__ BIASb,
    u16* __restrict__ O)
{
    __shared__ __align__(16) u16 sQ[64 * 40];    // 5 KB
    __shared__ __align__(16) u16 sK[128 * 40];   // 10 KB
    __shared__ __align__(16) u16 sVt[32 * 152];  // 9.5 KB
    __shared__ __align__(16) u16 sP[64 * 136];   // bias tile, then P (17 KB)

    int tid = threadIdx.x;
    int h = blockIdx.x & 3, w = (blockIdx.x >> 2) & 127, b = blockIdx.x >> 9;
    size_t rowbase = (size_t)b * N_ + w * QW;
    size_t bbase = ((size_t)(b * NWIN + w) * HEADS + h) * (QW * KW);
    const short8 zero8 = (short8){0, 0, 0, 0, 0, 0, 0, 0};
    const bool edge = (w == 0) || (w == NWIN - 1);

    {   // Q
        int r = tid >> 2, d8 = (tid & 3) * 8;
        *(short8*)&sQ[r * 40 + d8] =
            *(const short8*)&QKV[(rowbase + r) * 384 + h * DH + d8];
    }
    #pragma unroll
    for (int i = 0; i < 2; ++i) {  // K
        int idx = tid + i * 256;
        int r = idx >> 2, d8 = (idx & 3) * 8;
        int jk = w * QW + r - PADW;
        short8 v = zero8;
        if (jk >= 0 && jk < N_)
            v = *(const short8*)&QKV[((size_t)b * N_ + jk) * 384 + 128 + h * DH + d8];
        *(short8*)&sK[r * 40 + d8] = v;
    }
    {   // V transposed
        int kk = tid >> 1, d0 = (tid & 1) * 16;
        int jk = w * QW + kk - PADW;
        short8 v0 = zero8, v1 = zero8;
        if (jk >= 0 && jk < N_) {
            const u16* src = &QKV[((size_t)b * N_ + jk) * 384 + 256 + h * DH + d0];
            v0 = *(const short8*)src;
            v1 = *(const short8*)(src + 8);
        }
        #pragma unroll
        for (int j = 0; j < 8; ++j) {
            sVt[(d0 + j) * 152 + kk] = (u16)v0[j];
            sVt[(d0 + 8 + j) * 152 + kk] = (u16)v1[j];
        }
    }
    #pragma unroll
    for (int i = 0; i < 4; ++i) {  // bias tile -> sP [q][kk]
        int idx = tid + i * 256;
        int q = idx >> 4, c8 = idx & 15;
        *(short8*)&sP[q * 136 + c8 * 8] =
            *(const short8*)&BIASb[bbase + (size_t)q * KW + c8 * 8];
    }
    __syncthreads();  // the ONLY barrier

    int wv = tid >> 6, lane = tid & 63, quad = lane >> 4, l16 = lane & 15;
    const float scale = 0.17677669529663687f;  // 1/sqrt(32)
    int qrow = wv * 16 + l16;                  // this lane's q row (fixed)

    // ---- QK^T swapped: D[kk][q].  kk = kt*16 + quad*4 + r, q = qrow ----
    short8 aq = *(short8*)&sQ[qrow * 40 + quad * 8];
    float e[8][4];
    __builtin_amdgcn_s_setprio(1);
    #pragma unroll
    for (int kt = 0; kt < 8; ++kt) {
        short8 bk = *(short8*)&sK[(kt * 16 + l16) * 40 + quad * 8];
        f32x4v acc = (f32x4v){0.f, 0.f, 0.f, 0.f};
        acc = __builtin_amdgcn_mfma_f32_16x16x32_bf16(bk, aq, acc, 0, 0, 0);
        us4 bv = *(us4*)&sP[qrow * 136 + kt * 16 + quad * 4];  // 8B bias read
        #pragma unroll
        for (int r = 0; r < 4; ++r) {
            float msk = 0.f;
            if (edge) {
                int jk = w * QW + kt * 16 + quad * 4 + r - PADW;
                msk = (jk >= 0 && jk < N_) ? 0.f : -1e9f;
            }
            e[kt][r] = acc[r] * scale + b2f(bv[r]) + msk;
        }
    }
    __builtin_amdgcn_s_setprio(0);

    // ---- softmax: per-lane q; 32 in-lane + cross-quad shfl_xor(16,32) ----
    {
        float m = e[0][0];
        #pragma unroll
        for (int kt = 0; kt < 8; ++kt)
            #pragma unroll
            for (int r = 0; r < 4; ++r) m = fmaxf(m, e[kt][r]);
        m = fmaxf(m, __shfl_xor(m, 16));
        m = fmaxf(m, __shfl_xor(m, 32));
        float s = 0.f;
        #pragma unroll
        for (int kt = 0; kt < 8; ++kt)
            #pragma unroll
            for (int r = 0; r < 4; ++r) {
                float ev = __expf(e[kt][r] - m);
                e[kt][r] = ev;
                s += ev;
            }
        s += __shfl_xor(s, 16);
        s += __shfl_xor(s, 32);
        float inv = __builtin_amdgcn_rcpf(s);
        #pragma unroll
        for (int kt = 0; kt < 8; ++kt)
            #pragma unroll
            for (int r = 0; r < 4; ++r) e[kt][r] *= inv;
    }

    // ---- write P: lane owns (qrow, kk=kt*16+quad*4..+3) -> 8B writes ----
    #pragma unroll
    for (int kt = 0; kt < 8; ++kt)
        *(us4*)&sP[qrow * 136 + kt * 16 + quad * 4] =
            pack4(e[kt][0], e[kt][1], e[kt][2], e[kt][3]);

    // ---- P @ V (reads the wave's own rows; lgkmcnt-ordered, no barrier) ----
    short8 ap[4];
    #pragma unroll
    for (int ks = 0; ks < 4; ++ks)
        ap[ks] = *(short8*)&sP[qrow * 136 + ks * 32 + quad * 8];
    __builtin_amdgcn_s_setprio(1);
    #pragma unroll
    for (int nt = 0; nt < 2; ++nt) {
        f32x4v acc = (f32x4v){0.f, 0.f, 0.f, 0.f};
        #pragma unroll
        for (int ks = 0; ks < 4; ++ks) {
            short8 bv = *(short8*)&sVt[(nt * 16 + l16) * 152 + ks * 32 + quad * 8];
            acc = __builtin_amdgcn_mfma_f32_16x16x32_bf16(ap[ks], bv, acc, 0, 0, 0);
        }
        int d = nt * 16 + l16;
        #pragma unroll
        for (int r = 0; r < 4; ++r) {
            int q = wv * 16 + quad * 4 + r;
            O[(rowbase + q) * DS + h * DH + d] = f2b(acc[r]);
        }
    }
    __builtin_amdgcn_s_setprio(0);
}

// ---------------------------------------------------------------------------
// Segment mean (unchanged).
// ---------------------------------------------------------------------------
__global__ __launch_bounds__(128) void seg_kernel(
    const u16* __restrict__ TOKb, const int* __restrict__ idx,
    float* __restrict__ out)
{
    int t = blockIdx.x & (NT - 1);
    int b = blockIdx.x >> 10;
    const int* id = idx + (size_t)b * N_;

    int lo = 0, hi = N_;
    while (lo < hi) { int mid = (lo + hi) >> 1; if (id[mid] < t) lo = mid + 1; else hi = mid; }
    int start = lo;
    hi = N_;
    while (lo < hi) { int mid = (lo + hi) >> 1; if (id[mid] < t + 1) lo = mid + 1; else hi = mid; }
    int end = lo;

    float inv = 1.f / fmaxf((float)(end - start), 1.f);
    if (threadIdx.x < 96) {
        int c4 = threadIdx.x * 4;
        f32x4v s = (f32x4v){0.f, 0.f, 0.f, 0.f};
        for (int r = start; r < end; ++r) {
            us4 v = *(const us4*)&TOKb[((size_t)b * N_ + r) * DT + c4];
            s[0] += b2f(v[0]); s[1] += b2f(v[1]);
            s[2] += b2f(v[2]); s[3] += b2f(v[3]);
        }
        s[0] *= inv; s[1] *= inv; s[2] *= inv; s[3] *= inv;
        *(f32x4v*)&out[((size_t)b * NT + t) * DT + c4] = s;
    }
}

// ---------------------------------------------------------------------------
extern "C" void kernel_launch(void* const* d_in, const int* in_sizes, int n_in,
                              void* d_out, int out_size, void* d_ws, size_t ws_size,
                              hipStream_t stream)
{
    const float* ref_pos    = (const float*)d_in[0];
    const float* ref_charge = (const float*)d_in[1];
    const float* ref_mask   = (const float*)d_in[2];
    const float* ref_elem   = (const float*)d_in[3];
    const float* ref_chars  = (const float*)d_in[4];
    const float* W_single   = (const float*)d_in[5];
    const float* W_pair     = (const float*)d_in[6];
    const float* W_outer    = (const float*)d_in[7];
    const float* Wp_ff1     = (const float*)d_in[8];
    const float* Wp_ff2     = (const float*)d_in[9];
    const float* Wq         = (const float*)d_in[10];
    const float* Wk         = (const float*)d_in[11];
    const float* Wv         = (const float*)d_in[12];
    const float* Wo         = (const float*)d_in[13];
    const float* Wb         = (const float*)d_in[14];
    const float* Wff1       = (const float*)d_in[15];
    const float* Wff2       = (const float*)d_in[16];
    const float* W_out      = (const float*)d_in[17];
    const int*   uid        = (const int*)d_in[18];
    const int*   a2t        = (const int*)d_in[19];
    float* out = (float*)d_out;

    const size_t ROWS = (size_t)B_ * N_;  // 16384
    float* ws = (float*)d_ws;
    float* X    = ws;
    float* P    = X + ROWS * DS;
    u16* QKVb   = (u16*)(P + ROWS * 32);
    u16* Ob     = QKVb + ROWS * 384;
    u16* FFb    = Ob + ROWS * DS;          // unused (layout stability)
    u16* BIASb  = FFb + ROWS * 512;
    u16* TOKb   = BIASb + (size_t)B_ * NWIN * HEADS * QW * KW;
    u16* LNb    = TOKb + ROWS * DT;        // unused
    u16* qkvT   = LNb + ROWS * DS;
    u16* woT    = qkvT + 3 * 384 * 128;
    u16* ff1T   = woT + 3 * 128 * 128;
    u16* ff2T   = ff1T + 3 * 512 * 128;
    u16* woutT  = ff2T + 3 * 128 * 512;
    u16* w1T32  = woutT + 384 * 128;
    u16* wcatT  = w1T32 + 64 * 32;
    u16* wsT    = wcatT + 16 * 96;
    u16* woutrT = wsT + 128 * 416;

    convw_kernel<<<768, 256, 0, stream>>>(Wq, Wk, Wv, Wo, Wff1, Wff2, W_out,
                                          Wp_ff1, Wp_ff2, Wb, W_single, W_outer,
                                          qkvT, woT, ff1T, ff2T, woutT,
                                          w1T32, wcatT, wsT, woutrT);
    embed_gemm<<<ROWS / 64, 256, 0, stream>>>(ref_pos, ref_charge, ref_mask,
                                              ref_elem, ref_chars, wsT, woutrT,
                                              qkvT, X, P, QKVb);
    bias_kernel<<<4096, 256, 0, stream>>>(ref_pos, uid, P, W_pair,
                                          w1T32, wcatT, BIASb);

    for (int l = 0; l < DEPTH; ++l) {
        attn_kernel<<<B_ * NWIN * HEADS, 256, 0, stream>>>(QKVb, BIASb, Ob);
        if (l < DEPTH - 1) {
            wo_ff_fused<false><<<ROWS / 32, 256, 0, stream>>>(
                Ob, woT + (size_t)l * 128 * 128,
                ff1T + (size_t)l * 512 * 128, ff2T + (size_t)l * 128 * 512,
                qkvT + (size_t)(l + 1) * 384 * 128, X, QKVb);
        } else {
            wo_ff_fused<true><<<ROWS / 32, 256, 0, stream>>>(
                Ob, woT + (size_t)l * 128 * 128,
                ff1T + (size_t)l * 512 * 128, ff2T + (size_t)l * 128 * 512,
                woutT, X, TOKb);
        }
    }

    seg_kernel<<<B_ * NT, 128, 0, stream>>>(TOKb, a2t, out);
}